// Round 7
// baseline (606.548 us; speedup 1.0000x reference)
//
#include <hip/hip_runtime.h>
#include <hip/hip_bf16.h>
#include <cstddef>

#define B_   16
#define N_   1024
#define H_   2
#define D_   128
#define A_   256
#define FFN_ 1024
#define M_   (B_ * N_)   // 16384 rows
#define EPS_ 1e-5f
#define SPLIT 4
#define KT   32                    // keys per tile
#define TPC  (N_ / SPLIT / KT)     // tiles per chunk = 8
#define QKV_E ((size_t)B_ * H_ * N_ * D_)

typedef short  short8  __attribute__((ext_vector_type(8)));
typedef float  f32x16  __attribute__((ext_vector_type(16)));
typedef unsigned int uint;
typedef unsigned short ushort;

#define MFMA32(a, b, c) __builtin_amdgcn_mfma_f32_32x32x16_bf16(a, b, c, 0, 0, 0)

__device__ __forceinline__ uint f2b1(float x) {
    uint u = __float_as_uint(x);
    return (u + 0x7fffu + ((u >> 16) & 1u)) >> 16;
}
__device__ __forceinline__ uint f2b2(float lo, float hi) {
    return f2b1(lo) | (f2b1(hi) << 16);
}
__device__ __forceinline__ float b2f(ushort u) {
    return __uint_as_float(((uint)u) << 16);
}

// global -> LDS direct DMA, 16B per lane. lds ptr must be wave-uniform.
__device__ __forceinline__ void gld16(const ushort* g, ushort* l) {
    __builtin_amdgcn_global_load_lds(
        (const __attribute__((address_space(1))) void*)g,
        (__attribute__((address_space(3))) void*)l, 16, 0, 0);
}

// ---------------------------------------------------------------------------
// fp32 -> bf16 bulk convert (8 elems/thread)
// ---------------------------------------------------------------------------
__global__ __launch_bounds__(256) void f32_to_bf16_kernel(
    const float* __restrict__ in, ushort* __restrict__ out)
{
    const size_t i = ((size_t)blockIdx.x * 256 + threadIdx.x) * 8;
    float4 a = *(const float4*)(in + i);
    float4 b = *(const float4*)(in + i + 4);
    uint4 w = { f2b2(a.x, a.y), f2b2(a.z, a.w), f2b2(b.x, b.y), f2b2(b.z, b.w) };
    *(uint4*)(out + i) = w;
}

// ---------------------------------------------------------------------------
// Weight prep: W[K][N] fp32 -> Wt[N][K] bf16, blockIdx.z = layer (strided)
// ---------------------------------------------------------------------------
__global__ __launch_bounds__(256) void transpose_bf16_kernel(
    const float* __restrict__ W, ushort* __restrict__ Wt, int K, int N,
    size_t sstride, size_t dstride)
{
    __shared__ float tile[32][33];
    W  += (size_t)blockIdx.z * sstride;
    Wt += (size_t)blockIdx.z * dstride;
    const int n0 = blockIdx.x * 32, k0 = blockIdx.y * 32;
    const int tc = threadIdx.x & 31, tr = threadIdx.x >> 5;
#pragma unroll
    for (int it = 0; it < 4; ++it) {
        int r = it * 8 + tr;
        tile[r][tc] = W[(size_t)(k0 + r) * N + n0 + tc];
    }
    __syncthreads();
#pragma unroll
    for (int it = 0; it < 4; ++it) {
        int r = it * 8 + tr;
        Wt[(size_t)(n0 + r) * K + k0 + tc] = (ushort)f2b1(tile[tc][r]);
    }
}

// packed QKV transpose: z = layer*3 + sec
__global__ __launch_bounds__(256) void transpose_qkv_kernel(
    const float* __restrict__ Wq, const float* __restrict__ Wk,
    const float* __restrict__ Wv, ushort* __restrict__ dst)
{
    __shared__ float tile[32][33];
    const int layer = blockIdx.z / 3, sec = blockIdx.z % 3;
    const float* W = (sec == 0 ? Wq : sec == 1 ? Wk : Wv) + (size_t)layer * A_ * A_;
    ushort* out = dst + (size_t)layer * (3 * A_ * A_) + (size_t)sec * A_ * A_;
    const int n0 = blockIdx.x * 32, k0 = blockIdx.y * 32;
    const int tc = threadIdx.x & 31, tr = threadIdx.x >> 5;
#pragma unroll
    for (int it = 0; it < 4; ++it) {
        int r = it * 8 + tr;
        tile[r][tc] = W[(size_t)(k0 + r) * A_ + n0 + tc];
    }
    __syncthreads();
#pragma unroll
    for (int it = 0; it < 4; ++it) {
        int r = it * 8 + tr;
        out[(size_t)(n0 + r) * A_ + k0 + tc] = (ushort)f2b1(tile[tc][r]);
    }
}

// ---------------------------------------------------------------------------
// MFMA GEMM, T3-minimum 2-phase pipeline:
//   prologue STAGE(buf0); per tile: STAGE(next -> buf^1) || compute(buf);
//   vmcnt(0)+barrier once per tile (loads fly during compute).
// Staging via global_load_lds w16; linear LDS + XOR-granule swizzle on the
// global source AND the ds_read side (both-sides rule).
// modes: 1 = relu fp32 (ldc)   2 = relu bf16 (ldc)
//        5 = fused QKV: q heads / k heads / v transposed [bh][d][n]
// ---------------------------------------------------------------------------
__global__ __launch_bounds__(256) void gemm_mfma(
    const ushort* __restrict__ Asrc, const ushort* __restrict__ Wt,
    const float* __restrict__ bias, const float* __restrict__ biasK,
    const float* __restrict__ biasV, void* __restrict__ outp,
    int K, int ldc, int mode)
{
    __shared__ ushort sA[2][128 * 64];
    __shared__ ushort sB[2][128 * 64];

    const int tid = threadIdx.x;
    const int wid = tid >> 6, lane = tid & 63;
    const int c = lane & 31, g = lane >> 5;
    const int wr = wid >> 1, wc = wid & 1;
    const int m0 = blockIdx.x * 128;
    const int n0 = blockIdx.y * 128;

    f32x16 acc[2][2] = {};

#define STAGE(bf, k0) {                                                        \
    _Pragma("unroll")                                                          \
    for (int it = 0; it < 4; ++it) {                                           \
        const int idx = (wid * 4 + it) * 64 + lane;                            \
        const int r = idx >> 3, gg = idx & 7;                                  \
        const int srcoff = ((gg ^ (r & 7)) << 3);                              \
        gld16(Asrc + (size_t)(m0 + r) * K + (k0) + srcoff,                     \
              &sA[bf][(wid * 4 + it) << 9]);                                   \
        gld16(Wt + (size_t)(n0 + r) * K + (k0) + srcoff,                       \
              &sB[bf][(wid * 4 + it) << 9]);                                   \
    } }

    const int nt = K >> 6;
    int buf = 0;
    STAGE(0, 0);
    asm volatile("s_waitcnt vmcnt(0)" ::: "memory");
    __syncthreads();

    for (int t = 0; t < nt; ++t) {
        if (t + 1 < nt) STAGE(buf ^ 1, (t + 1) << 6);
#pragma unroll
        for (int ks = 0; ks < 4; ++ks) {
            const int swz = (((ks * 2 + g) ^ (c & 7)) << 3);
            short8 a0 = *(const short8*)&sA[buf][(wr * 64 + c) * 64 + swz];
            short8 a1 = *(const short8*)&sA[buf][(wr * 64 + 32 + c) * 64 + swz];
            short8 b0 = *(const short8*)&sB[buf][(wc * 64 + c) * 64 + swz];
            short8 b1 = *(const short8*)&sB[buf][(wc * 64 + 32 + c) * 64 + swz];
            acc[0][0] = MFMA32(a0, b0, acc[0][0]);
            acc[0][1] = MFMA32(a0, b1, acc[0][1]);
            acc[1][0] = MFMA32(a1, b0, acc[1][0]);
            acc[1][1] = MFMA32(a1, b1, acc[1][1]);
        }
        if (t + 1 < nt) {
            asm volatile("s_waitcnt vmcnt(0)" ::: "memory");
            __syncthreads();
            buf ^= 1;
        }
    }
#undef STAGE

    const int sec = n0 >> 8;  // for mode 5 (block-uniform)
    const float* bp = bias;
    int nw = n0;
    if (mode == 5) {
        bp = (sec == 0 ? bias : sec == 1 ? biasK : biasV);
        nw = n0 & 255;
    }
    const float bz[2] = { bp[nw + wc * 64 + c], bp[nw + wc * 64 + 32 + c] };

#pragma unroll
    for (int mr = 0; mr < 2; ++mr) {
#pragma unroll
        for (int ct = 0; ct < 2; ++ct) {
            const int colbase = n0 + wc * 64 + ct * 32 + c;
#pragma unroll
            for (int rg = 0; rg < 4; ++rg) {
                const int row = m0 + wr * 64 + mr * 32 + 8 * rg + 4 * g;
                float v0 = acc[mr][ct][4 * rg + 0] + bz[ct];
                float v1 = acc[mr][ct][4 * rg + 1] + bz[ct];
                float v2 = acc[mr][ct][4 * rg + 2] + bz[ct];
                float v3 = acc[mr][ct][4 * rg + 3] + bz[ct];
                if (mode == 1 || mode == 2) {
                    v0 = fmaxf(v0, 0.f); v1 = fmaxf(v1, 0.f);
                    v2 = fmaxf(v2, 0.f); v3 = fmaxf(v3, 0.f);
                }
                if (mode == 1) {
                    float* o = (float*)outp;
                    o[(size_t)(row + 0) * ldc + colbase] = v0;
                    o[(size_t)(row + 1) * ldc + colbase] = v1;
                    o[(size_t)(row + 2) * ldc + colbase] = v2;
                    o[(size_t)(row + 3) * ldc + colbase] = v3;
                } else if (mode == 2) {
                    ushort* o = (ushort*)outp;
                    o[(size_t)(row + 0) * ldc + colbase] = (ushort)f2b1(v0);
                    o[(size_t)(row + 1) * ldc + colbase] = (ushort)f2b1(v1);
                    o[(size_t)(row + 2) * ldc + colbase] = (ushort)f2b1(v2);
                    o[(size_t)(row + 3) * ldc + colbase] = (ushort)f2b1(v3);
                } else {  // mode 5
                    const int cw = colbase & 255;
                    const int hh = cw >> 7, dd = cw & (D_ - 1);
                    if (sec < 2) {
                        ushort* o = (ushort*)outp + (size_t)sec * QKV_E;
#pragma unroll
                        for (int r2 = 0; r2 < 4; ++r2) {
                            int rw = row + r2;
                            int bb = rw >> 10, np = rw & (N_ - 1);
                            float vv = (r2 == 0 ? v0 : r2 == 1 ? v1 : r2 == 2 ? v2 : v3);
                            o[(((size_t)(bb * H_ + hh) * N_ + np) * D_) + dd] = (ushort)f2b1(vv);
                        }
                    } else {
                        ushort* o = (ushort*)outp + 2 * QKV_E;
                        const int bb = row >> 10, np = row & (N_ - 1);
                        uint2 w = { f2b2(v0, v1), f2b2(v2, v3) };
                        *(uint2*)(o + ((size_t)(bb * H_ + hh) * D_ + dd) * N_ + np) = w;
                    }
                }
            }
        }
    }
}

// ---------------------------------------------------------------------------
// Flash attention with grid split-KV + XCD-swizzled 1D grid.
// block = 128 thr (2 waves x 32 queries), KV chunk = 256 keys, tile = 32 keys.
// Prefetch in named regs, PINNED with sched_barrier(0) (compiler sank it in
// R5 -> VGPR 84 proved no overlap). Dual S-accumulator chains; setprio around
// MFMA clusters.
// ---------------------------------------------------------------------------
#define KPITCH 132
#define VPITCH 36
#define OPITCH 132   // epilogue overlay pitch

__global__ __launch_bounds__(128) void attn_kernel(
    const ushort* __restrict__ qg, const ushort* __restrict__ kg,
    const ushort* __restrict__ vtg, ushort* __restrict__ po,
    float* __restrict__ pm, float* __restrict__ pl)
{
    __shared__ ushort smem[KT * KPITCH + 128 * VPITCH];   // 17664 B
    ushort* sK  = smem;                  // [32 keys][KPITCH]
    ushort* sVt = smem + KT * KPITCH;    // [128 d][VPITCH]
    ushort* sO  = smem;                  // epilogue overlay [64 q][OPITCH]

    const int tid = threadIdx.x;
    const int w = tid >> 6, lane = tid & 63;
    const int c = lane & 31, g = lane >> 5;

    // XCD-aware decomposition: keep all 16 q-tiles of one (bh,z) on one XCD
    const int flat = blockIdx.x;          // 0..2047
    const int xcd  = flat & 7;
    const int ii   = flat >> 3;           // 0..255
    const int pair = xcd * 16 + (ii & 15);// 0..127 = (z,bh)
    const int qt   = ii >> 4;             // 0..15
    const int bh   = pair & 31;
    const int z    = pair >> 5;

    const int q0 = qt * 64 + w * 32;
    const size_t bhoff = (size_t)bh * (N_ * D_);
    const int kt0 = z * (N_ / SPLIT);
    const float scale2 = 0.08838834764831845f * 1.44269504f;  // /sqrt(128)*log2e
    const float THR = 11.5f;

    short8 qf[8];
    const ushort* qrow = qg + bhoff + (size_t)(q0 + c) * D_;
#pragma unroll
    for (int ks = 0; ks < 8; ++ks)
        qf[ks] = *(const short8*)(qrow + ks * 16 + 8 * g);

    f32x16 oacc[4] = {};
    float m = -1e30f, l = 0.f;

    // named staging registers (rule #20: NO arrays, NO lambdas)
    uint4 kr0, kr1, kr2, kr3, vr0, vr1, vr2, vr3;
    const int krow = tid >> 4, kcol = (tid & 15) * 8;     // K addressing
    const int vrow = tid >> 2, vcol = (tid & 3) * 8;      // V addressing

#define LOADKV(t) { \
    const ushort* ks_ = kg + bhoff + (size_t)(kt0 + (t) * KT) * D_; \
    kr0 = *(const uint4*)(ks_ + (size_t)(krow     ) * D_ + kcol); \
    kr1 = *(const uint4*)(ks_ + (size_t)(krow +  8) * D_ + kcol); \
    kr2 = *(const uint4*)(ks_ + (size_t)(krow + 16) * D_ + kcol); \
    kr3 = *(const uint4*)(ks_ + (size_t)(krow + 24) * D_ + kcol); \
    const ushort* vs_ = vtg + bhoff + kt0 + (t) * KT; \
    vr0 = *(const uint4*)(vs_ + (size_t)(vrow     ) * N_ + vcol); \
    vr1 = *(const uint4*)(vs_ + (size_t)(vrow + 32) * N_ + vcol); \
    vr2 = *(const uint4*)(vs_ + (size_t)(vrow + 64) * N_ + vcol); \
    vr3 = *(const uint4*)(vs_ + (size_t)(vrow + 96) * N_ + vcol); }

#define WLDS() { \
    *(uint4*)&sK[(krow     ) * KPITCH + kcol] = kr0; \
    *(uint4*)&sK[(krow +  8) * KPITCH + kcol] = kr1; \
    *(uint4*)&sK[(krow + 16) * KPITCH + kcol] = kr2; \
    *(uint4*)&sK[(krow + 24) * KPITCH + kcol] = kr3; \
    *(uint4*)&sVt[(vrow     ) * VPITCH + vcol] = vr0; \
    *(uint4*)&sVt[(vrow + 32) * VPITCH + vcol] = vr1; \
    *(uint4*)&sVt[(vrow + 64) * VPITCH + vcol] = vr2; \
    *(uint4*)&sVt[(vrow + 96) * VPITCH + vcol] = vr3; }

    LOADKV(0);
    WLDS();
    __syncthreads();

    for (int t = 0; t < TPC; ++t) {
        if (t + 1 < TPC) {
            LOADKV(t + 1);                         // issue early...
            __builtin_amdgcn_sched_barrier(0);     // ...and PIN (no sinking)
        }

        // ---- S^T = K · Q^T  (two independent accumulator chains) ----
        f32x16 sacc0 = {}, sacc1 = {};
        __builtin_amdgcn_s_setprio(1);
#pragma unroll
        for (int ks = 0; ks < 4; ++ks) {
            short8 a0 = *(const short8*)&sK[c * KPITCH + (2 * ks) * 16 + 8 * g];
            short8 a1 = *(const short8*)&sK[c * KPITCH + (2 * ks + 1) * 16 + 8 * g];
            sacc0 = MFMA32(a0, qf[2 * ks], sacc0);
            sacc1 = MFMA32(a1, qf[2 * ks + 1], sacc1);
        }
        __builtin_amdgcn_s_setprio(0);

        // ---- online softmax (exp2 domain, defer-max) ----
        float p[16];
        float tmax = -1e30f;
#pragma unroll
        for (int r = 0; r < 16; ++r) {
            float s = (sacc0[r] + sacc1[r]) * scale2;
            p[r] = s;
            tmax = fmaxf(tmax, s);
        }
        tmax = fmaxf(tmax, __shfl_xor(tmax, 32, 64));
        if (!__all(tmax - m <= THR)) {
            const float mnew = fmaxf(m, tmax);
            const float corr = exp2f(m - mnew);
#pragma unroll
            for (int dt = 0; dt < 4; ++dt)
#pragma unroll
                for (int r = 0; r < 16; ++r) oacc[dt][r] *= corr;
            l *= corr;
            m = mnew;
        }
        float tsum = 0.f;
#pragma unroll
        for (int r = 0; r < 16; ++r) {
            p[r] = exp2f(p[r] - m);
            tsum += p[r];
        }
        tsum += __shfl_xor(tsum, 32, 64);
        l += tsum;

        uint pk[8];
#pragma unroll
        for (int pp = 0; pp < 8; ++pp)
            pk[pp] = f2b2(p[2 * pp], p[2 * pp + 1]);

        uint v0 = g ? pk[0] : pk[2];
        uint v1 = g ? pk[1] : pk[3];
        uint v2 = g ? pk[4] : pk[6];
        uint v3 = g ? pk[5] : pk[7];
        uint r0 = (uint)__shfl_xor((int)v0, 32, 64);
        uint r1 = (uint)__shfl_xor((int)v1, 32, 64);
        uint r2 = (uint)__shfl_xor((int)v2, 32, 64);
        uint r3 = (uint)__shfl_xor((int)v3, 32, 64);

        // ---- O^T += V^T · P^T ----
        __builtin_amdgcn_s_setprio(1);
#pragma unroll
        for (int kb = 0; kb < 2; ++kb) {
            union { uint u[4]; short8 s; } pf;
            if (kb == 0) {
                pf.u[0] = g ? r0 : pk[0];
                pf.u[1] = g ? r1 : pk[1];
                pf.u[2] = g ? pk[2] : r0;
                pf.u[3] = g ? pk[3] : r1;
            } else {
                pf.u[0] = g ? r2 : pk[4];
                pf.u[1] = g ? r3 : pk[5];
                pf.u[2] = g ? pk[6] : r2;
                pf.u[3] = g ? pk[7] : r3;
            }
#pragma unroll
            for (int dt = 0; dt < 4; ++dt) {
                short8 a = *(const short8*)&sVt[(dt * 32 + c) * VPITCH + kb * 16 + 8 * g];
                oacc[dt] = MFMA32(a, pf.s, oacc[dt]);
            }
        }
        __builtin_amdgcn_s_setprio(0);

        __syncthreads();
        if (t + 1 < TPC) { WLDS(); __syncthreads(); }
    }

    // ---- epilogue: LDS transpose -> coalesced bf16 partial-O write ----
    if (lane < 32) {
        pm[(size_t)(z * 32 + bh) * N_ + q0 + c] = m;
        pl[(size_t)(z * 32 + bh) * N_ + q0 + c] = l;
    }
    {
        const int qrl = w * 32 + c;
#pragma unroll
        for (int dt = 0; dt < 4; ++dt)
#pragma unroll
            for (int rg = 0; rg < 4; ++rg) {
                int d = dt * 32 + 8 * rg + 4 * g;
                uint2 pv = { f2b2(oacc[dt][4 * rg + 0], oacc[dt][4 * rg + 1]),
                             f2b2(oacc[dt][4 * rg + 2], oacc[dt][4 * rg + 3]) };
                *(uint2*)&sO[qrl * OPITCH + d] = pv;
            }
    }
    __syncthreads();
    {
        const size_t pbase = ((size_t)(z * 32 + bh) * N_ + qt * 64) * D_;
#pragma unroll
        for (int it = 0; it < 16; ++it) {
            int idx = it * 128 + tid;            // 0..2047 (8B granules)
            int r = idx >> 5, dgr = (idx & 31) * 4;
            uint2 v = *(const uint2*)&sO[r * OPITCH + dgr];
            *(uint2*)(po + pbase + (size_t)r * D_ + dgr) = v;
        }
    }
#undef LOADKV
#undef WLDS
}

// ---------------------------------------------------------------------------
// Combine split-KV partials -> bf16 [b][n][A] (feeds FFN1 directly)
// ---------------------------------------------------------------------------
__global__ __launch_bounds__(256) void combine_kernel(
    const ushort* __restrict__ po, const float* __restrict__ pm,
    const float* __restrict__ pl, ushort* __restrict__ out)
{
    const int idx = blockIdx.x * 256 + threadIdx.x;
    const int row = idx >> 7, d = idx & 127;
    const int R = B_ * H_ * N_;  // 32768

    float ms[SPLIT];
    float M = -1e30f;
#pragma unroll
    for (int s = 0; s < SPLIT; ++s) {
        ms[s] = pm[(size_t)s * R + row];
        M = fmaxf(M, ms[s]);
    }
    float L = 0.f, acc = 0.f;
#pragma unroll
    for (int s = 0; s < SPLIT; ++s) {
        float wgt = exp2f(ms[s] - M);
        L += pl[(size_t)s * R + row] * wgt;
        acc += b2f(po[((size_t)s * R + row) * D_ + d]) * wgt;
    }
    const int bh = row >> 10, n = row & (N_ - 1);
    const int bb = bh >> 1, hh = bh & 1;
    out[((size_t)(bb * N_ + n)) * A_ + hh * D_ + d] = (ushort)f2b1(acc / L);
}

// ---------------------------------------------------------------------------
// step = LayerNorm(roll + prev)*g+b  -> fp32 (residual) + bf16 (GEMM A)
// ---------------------------------------------------------------------------
__global__ __launch_bounds__(256) void add_ln_kernel(
    const float* __restrict__ roll, const float* __restrict__ prev,
    const float* __restrict__ g, const float* __restrict__ bta,
    float* __restrict__ out, ushort* __restrict__ outb)
{
    const int row = blockIdx.x, tid = threadIdx.x;
    float v = roll[(size_t)row * A_ + tid] + prev[(size_t)row * A_ + tid];
    float s = v, s2 = v * v;
#pragma unroll
    for (int o = 32; o > 0; o >>= 1) {
        s  += __shfl_down(s, o, 64);
        s2 += __shfl_down(s2, o, 64);
    }
    __shared__ float ps[4], ps2[4];
    __shared__ float mu_s, rsig_s;
    const int wid = tid >> 6, lane = tid & 63;
    if (lane == 0) { ps[wid] = s; ps2[wid] = s2; }
    __syncthreads();
    if (tid == 0) {
        float S  = ps[0] + ps[1] + ps[2] + ps[3];
        float S2 = ps2[0] + ps2[1] + ps2[2] + ps2[3];
        float mu = S / A_;
        float var = S2 / A_ - mu * mu;
        mu_s = mu;
        rsig_s = rsqrtf(var + EPS_);
    }
    __syncthreads();
    float y = (v - mu_s) * rsig_s * g[tid] + bta[tid];
    out[(size_t)row * A_ + tid] = y;
    outb[(size_t)row * A_ + tid] = (ushort)f2b1(y);
}

// ---------------------------------------------------------------------------
__global__ __launch_bounds__(256) void pool_kernel(
    const float* __restrict__ ent, float* __restrict__ part)
{
    const int b = blockIdx.x, s = blockIdx.y, a = threadIdx.x;
    float acc = 0.f;
    for (int n = s * 32; n < s * 32 + 32; ++n)
        acc += ent[((size_t)b * N_ + n) * A_ + a];
    part[((size_t)b * 32 + s) * A_ + a] = acc;
}

__global__ __launch_bounds__(256) void final_kernel(
    const float* __restrict__ part, const float* __restrict__ We,
    const float* __restrict__ be, float* __restrict__ out)
{
    __shared__ float sp[A_];
    const int b = blockIdx.x, tid = threadIdx.x;
    float s = 0.f;
    for (int j = 0; j < 32; ++j) s += part[((size_t)b * 32 + j) * A_ + tid];
    sp[tid] = s * (1.0f / N_);
    __syncthreads();
    float acc = be[tid];
    for (int kk = 0; kk < A_; ++kk) acc += sp[kk] * We[(size_t)kk * A_ + tid];
    out[b * A_ + tid] = fmaxf(acc, 0.f);
}

// ---------------------------------------------------------------------------
extern "C" void kernel_launch(void* const* d_in, const int* in_sizes, int n_in,
                              void* d_out, int out_size, void* d_ws, size_t ws_size,
                              hipStream_t stream)
{
    const float* X    = (const float*)d_in[0];
    const float* Wq   = (const float*)d_in[1];
    const float* bq   = (const float*)d_in[2];
    const float* Wk   = (const float*)d_in[3];
    const float* bk   = (const float*)d_in[4];
    const float* Wv   = (const float*)d_in[5];
    const float* bv   = (const float*)d_in[6];
    const float* W1   = (const float*)d_in[7];
    const float* b1   = (const float*)d_in[8];
    const float* W2   = (const float*)d_in[9];
    const float* b2   = (const float*)d_in[10];
    const float* ln_g = (const float*)d_in[11];
    const float* ln_b = (const float*)d_in[12];
    const float* Wc   = (const float*)d_in[13];
    const float* bc   = (const float*)d_in[14];
    const float* We   = (const float*)d_in[15];
    const float* be   = (const float*)d_in[16];

    // ---- workspace layout (~107 MB) ----
    char* base = (char*)d_ws;
    ushort* qb     = (ushort*)base;  base += QKV_E * 2;   // q; attnb alias
    /* kb */                         base += QKV_E * 2;
    /* vt */                         base += QKV_E * 2;
    ushort* hbuf   = (ushort*)base;  base += (size_t)M_ * FFN_ * 2;  // aliases po/ent
    float*  attn   = (float*)base;   base += (size_t)M_ * A_ * 4;    // roll fp32
    float*  step   = (float*)base;   base += (size_t)M_ * A_ * 4;
    ushort* stepb  = (ushort*)base;  base += (size_t)M_ * A_ * 2;
    ushort* wqkv_t = (ushort*)base;  base += (size_t)3 * 3 * A_ * A_ * 2;
    ushort* w1_t   = (ushort*)base;  base += (size_t)3 * A_ * FFN_ * 2;
    ushort* w2_t   = (ushort*)base;  base += (size_t)3 * FFN_ * A_ * 2;
    ushort* wc_t   = (ushort*)base;  base += (size_t)A_ * A_ * 2;
    float*  part   = (float*)base;   base += (size_t)B_ * 32 * A_ * 4;
    float*  pm     = (float*)base;   base += (size_t)SPLIT * B_ * H_ * N_ * 4;
    float*  pl     = (float*)base;   base += (size_t)SPLIT * B_ * H_ * N_ * 4;
    ushort* kbuf   = qb + QKV_E;
    ushort* vtbuf  = qb + 2 * QKV_E;
    ushort* po     = hbuf;           // partial O: dead before FFN1 writes hbuf
    ushort* attnb  = qb;             // combine out: q dead after attn_kernel
    float*  ent    = (float*)hbuf;   // head output reuses hbuf

    // ---- weight/input prep ----
    transpose_qkv_kernel<<<dim3(8, 8, 9), 256, 0, stream>>>(Wq, Wk, Wv, wqkv_t);
    transpose_bf16_kernel<<<dim3(FFN_/32, A_/32, 3), 256, 0, stream>>>(
        W1, w1_t, A_, FFN_, (size_t)A_ * FFN_, (size_t)A_ * FFN_);
    transpose_bf16_kernel<<<dim3(A_/32, FFN_/32, 3), 256, 0, stream>>>(
        W2, w2_t, FFN_, A_, (size_t)FFN_ * A_, (size_t)FFN_ * A_);
    transpose_bf16_kernel<<<dim3(A_/32, A_/32, 1), 256, 0, stream>>>(
        Wc, wc_t, A_, A_, 0, 0);
    f32_to_bf16_kernel<<<(M_ * A_) / (256 * 8), 256, 0, stream>>>(X, stepb);

    const float* cur = X;   // fp32 residual input
    for (int i = 0; i < 3; ++i) {
        // fused QKV projection (A = stepb bf16)
        gemm_mfma<<<dim3(M_/128, 6), 256, 0, stream>>>(
            stepb, wqkv_t + (size_t)i * 3 * A_ * A_,
            bq + i * A_, bk + i * A_, bv + i * A_, qb, A_, 0, 5);

        attn_kernel<<<16 * SPLIT * B_ * H_, 128, 0, stream>>>(
            qb, kbuf, vtbuf, po, pm, pl);
        combine_kernel<<<(B_*H_*N_*D_)/256, 256, 0, stream>>>(po, pm, pl, attnb);

        gemm_mfma<<<dim3(M_/128, FFN_/128), 256, 0, stream>>>(
            attnb, w1_t + (size_t)i * A_ * FFN_, b1 + i * FFN_, nullptr, nullptr,
            hbuf, A_, FFN_, 2);
        gemm_mfma<<<dim3(M_/128, A_/128), 256, 0, stream>>>(
            hbuf, w2_t + (size_t)i * FFN_ * A_, b2 + i * A_, nullptr, nullptr,
            attn, FFN_, A_, 1);

        // writes step (fp32 residual) + stepb (bf16 A for next QKV / head)
        add_ln_kernel<<<M_, 256, 0, stream>>>(attn, cur, ln_g, ln_b, step, stepb);
        cur = step;
    }

    // head
    gemm_mfma<<<dim3(M_/128, A_/128), 256, 0, stream>>>(
        stepb, wc_t, bc, nullptr, nullptr, ent, A_, A_, 1);
    pool_kernel<<<dim3(B_, 32), 256, 0, stream>>>(ent, part);
    final_kernel<<<B_, 256, 0, stream>>>(part, We, be, (float*)d_out);
}

// Round 8
// 523.306 us; speedup vs baseline: 1.1591x; 1.1591x over previous
//
#include <hip/hip_runtime.h>
#include <hip/hip_bf16.h>
#include <cstddef>

#define B_   16
#define N_   1024
#define H_   2
#define D_   128
#define A_   256
#define FFN_ 1024
#define M_   (B_ * N_)   // 16384 rows
#define EPS_ 1e-5f
#define SPLIT 4
#define KT   32                    // keys per tile
#define TPC  (N_ / SPLIT / KT)     // tiles per chunk = 8
#define QKV_E ((size_t)B_ * H_ * N_ * D_)

typedef short  short8  __attribute__((ext_vector_type(8)));
typedef float  f32x16  __attribute__((ext_vector_type(16)));
typedef unsigned int uint;
typedef unsigned short ushort;

#define MFMA32(a, b, c) __builtin_amdgcn_mfma_f32_32x32x16_bf16(a, b, c, 0, 0, 0)

__device__ __forceinline__ uint f2b1(float x) {
    uint u = __float_as_uint(x);
    return (u + 0x7fffu + ((u >> 16) & 1u)) >> 16;
}
__device__ __forceinline__ uint f2b2(float lo, float hi) {
    return f2b1(lo) | (f2b1(hi) << 16);
}
__device__ __forceinline__ float b2f(ushort u) {
    return __uint_as_float(((uint)u) << 16);
}

// ---------------------------------------------------------------------------
// fp32 -> bf16 bulk convert (8 elems/thread)
// ---------------------------------------------------------------------------
__global__ __launch_bounds__(256) void f32_to_bf16_kernel(
    const float* __restrict__ in, ushort* __restrict__ out)
{
    const size_t i = ((size_t)blockIdx.x * 256 + threadIdx.x) * 8;
    float4 a = *(const float4*)(in + i);
    float4 b = *(const float4*)(in + i + 4);
    uint4 w = { f2b2(a.x, a.y), f2b2(a.z, a.w), f2b2(b.x, b.y), f2b2(b.z, b.w) };
    *(uint4*)(out + i) = w;
}

// ---------------------------------------------------------------------------
// Weight prep: W[K][N] fp32 -> Wt[N][K] bf16, blockIdx.z = layer (strided)
// ---------------------------------------------------------------------------
__global__ __launch_bounds__(256) void transpose_bf16_kernel(
    const float* __restrict__ W, ushort* __restrict__ Wt, int K, int N,
    size_t sstride, size_t dstride)
{
    __shared__ float tile[32][33];
    W  += (size_t)blockIdx.z * sstride;
    Wt += (size_t)blockIdx.z * dstride;
    const int n0 = blockIdx.x * 32, k0 = blockIdx.y * 32;
    const int tc = threadIdx.x & 31, tr = threadIdx.x >> 5;
#pragma unroll
    for (int it = 0; it < 4; ++it) {
        int r = it * 8 + tr;
        tile[r][tc] = W[(size_t)(k0 + r) * N + n0 + tc];
    }
    __syncthreads();
#pragma unroll
    for (int it = 0; it < 4; ++it) {
        int r = it * 8 + tr;
        Wt[(size_t)(n0 + r) * K + k0 + tc] = (ushort)f2b1(tile[tc][r]);
    }
}

// packed QKV transpose: z = layer*3 + sec
__global__ __launch_bounds__(256) void transpose_qkv_kernel(
    const float* __restrict__ Wq, const float* __restrict__ Wk,
    const float* __restrict__ Wv, ushort* __restrict__ dst)
{
    __shared__ float tile[32][33];
    const int layer = blockIdx.z / 3, sec = blockIdx.z % 3;
    const float* W = (sec == 0 ? Wq : sec == 1 ? Wk : Wv) + (size_t)layer * A_ * A_;
    ushort* out = dst + (size_t)layer * (3 * A_ * A_) + (size_t)sec * A_ * A_;
    const int n0 = blockIdx.x * 32, k0 = blockIdx.y * 32;
    const int tc = threadIdx.x & 31, tr = threadIdx.x >> 5;
#pragma unroll
    for (int it = 0; it < 4; ++it) {
        int r = it * 8 + tr;
        tile[r][tc] = W[(size_t)(k0 + r) * A_ + n0 + tc];
    }
    __syncthreads();
#pragma unroll
    for (int it = 0; it < 4; ++it) {
        int r = it * 8 + tr;
        out[(size_t)(n0 + r) * A_ + k0 + tc] = (ushort)f2b1(tile[tc][r]);
    }
}

// ---------------------------------------------------------------------------
// MFMA GEMM (R4-proven structure): reg-staged uint4 -> LDS pitch 72,
// single buffer, 2 barriers per K-chunk of 64.
// modes: 1 = relu fp32 (ldc)   2 = relu bf16 (ldc)
//        5 = fused QKV: q heads / k heads / v transposed [bh][d][n]
// ---------------------------------------------------------------------------
__global__ __launch_bounds__(256) void gemm_mfma(
    const ushort* __restrict__ Asrc, const ushort* __restrict__ Wt,
    const float* __restrict__ bias, const float* __restrict__ biasK,
    const float* __restrict__ biasV, void* __restrict__ outp,
    int K, int ldc, int mode)
{
    __shared__ ushort sA[128 * 72];
    __shared__ ushort sB[128 * 72];

    const int tid = threadIdx.x;
    const int wid = tid >> 6, lane = tid & 63;
    const int c = lane & 31, g = lane >> 5;
    const int wr = wid >> 1, wc = wid & 1;
    const int m0 = blockIdx.x * 128;
    const int n0 = blockIdx.y * 128;

    f32x16 acc[2][2] = {};

    for (int k0 = 0; k0 < K; k0 += 64) {
        __syncthreads();
#pragma unroll
        for (int it = 0; it < 4; ++it) {
            int idx = it * 256 + tid, r = idx >> 3, cc = (idx & 7) * 8;
            *(uint4*)&sA[r * 72 + cc] =
                *(const uint4*)(Asrc + (size_t)(m0 + r) * K + k0 + cc);
        }
#pragma unroll
        for (int it = 0; it < 4; ++it) {
            int idx = it * 256 + tid, r = idx >> 3, cc = (idx & 7) * 8;
            *(uint4*)&sB[r * 72 + cc] =
                *(const uint4*)(Wt + (size_t)(n0 + r) * K + k0 + cc);
        }
        __syncthreads();
#pragma unroll
        for (int ks = 0; ks < 4; ++ks) {
            const int ko = ks * 16 + 8 * g;
            short8 a0 = *(const short8*)&sA[(wr * 64 + c) * 72 + ko];
            short8 a1 = *(const short8*)&sA[(wr * 64 + 32 + c) * 72 + ko];
            short8 b0 = *(const short8*)&sB[(wc * 64 + c) * 72 + ko];
            short8 b1 = *(const short8*)&sB[(wc * 64 + 32 + c) * 72 + ko];
            acc[0][0] = MFMA32(a0, b0, acc[0][0]);
            acc[0][1] = MFMA32(a0, b1, acc[0][1]);
            acc[1][0] = MFMA32(a1, b0, acc[1][0]);
            acc[1][1] = MFMA32(a1, b1, acc[1][1]);
        }
    }

    const int sec = n0 >> 8;  // for mode 5 (block-uniform)
    const float* bp = bias;
    int nw = n0;
    if (mode == 5) {
        bp = (sec == 0 ? bias : sec == 1 ? biasK : biasV);
        nw = n0 & 255;
    }
    const float bz[2] = { bp[nw + wc * 64 + c], bp[nw + wc * 64 + 32 + c] };

#pragma unroll
    for (int mr = 0; mr < 2; ++mr) {
#pragma unroll
        for (int ct = 0; ct < 2; ++ct) {
            const int colbase = n0 + wc * 64 + ct * 32 + c;
#pragma unroll
            for (int rg = 0; rg < 4; ++rg) {
                const int row = m0 + wr * 64 + mr * 32 + 8 * rg + 4 * g;
                float v0 = acc[mr][ct][4 * rg + 0] + bz[ct];
                float v1 = acc[mr][ct][4 * rg + 1] + bz[ct];
                float v2 = acc[mr][ct][4 * rg + 2] + bz[ct];
                float v3 = acc[mr][ct][4 * rg + 3] + bz[ct];
                if (mode == 1 || mode == 2) {
                    v0 = fmaxf(v0, 0.f); v1 = fmaxf(v1, 0.f);
                    v2 = fmaxf(v2, 0.f); v3 = fmaxf(v3, 0.f);
                }
                if (mode == 1) {
                    float* o = (float*)outp;
                    o[(size_t)(row + 0) * ldc + colbase] = v0;
                    o[(size_t)(row + 1) * ldc + colbase] = v1;
                    o[(size_t)(row + 2) * ldc + colbase] = v2;
                    o[(size_t)(row + 3) * ldc + colbase] = v3;
                } else if (mode == 2) {
                    ushort* o = (ushort*)outp;
                    o[(size_t)(row + 0) * ldc + colbase] = (ushort)f2b1(v0);
                    o[(size_t)(row + 1) * ldc + colbase] = (ushort)f2b1(v1);
                    o[(size_t)(row + 2) * ldc + colbase] = (ushort)f2b1(v2);
                    o[(size_t)(row + 3) * ldc + colbase] = (ushort)f2b1(v3);
                } else {  // mode 5
                    const int cw = colbase & 255;
                    const int hh = cw >> 7, dd = cw & (D_ - 1);
                    if (sec < 2) {
                        ushort* o = (ushort*)outp + (size_t)sec * QKV_E;
#pragma unroll
                        for (int r2 = 0; r2 < 4; ++r2) {
                            int rw = row + r2;
                            int bb = rw >> 10, np = rw & (N_ - 1);
                            float vv = (r2 == 0 ? v0 : r2 == 1 ? v1 : r2 == 2 ? v2 : v3);
                            o[(((size_t)(bb * H_ + hh) * N_ + np) * D_) + dd] = (ushort)f2b1(vv);
                        }
                    } else {
                        ushort* o = (ushort*)outp + 2 * QKV_E;
                        const int bb = row >> 10, np = row & (N_ - 1);
                        uint2 w = { f2b2(v0, v1), f2b2(v2, v3) };
                        *(uint2*)(o + ((size_t)(bb * H_ + hh) * D_ + dd) * N_ + np) = w;
                    }
                }
            }
        }
    }
}

// ---------------------------------------------------------------------------
// Flash attention, BARRIER-FREE main loop: K and V fragments are read per-lane
// directly from global (L2-resident: one (bh,z) chunk = 128 KB, 16 blocks
// share it on one XCD). No LDS staging, no in-loop __syncthreads -> waves
// fully independent, TLP hides all load latency. LDS used only for the
// coalescing epilogue transpose.
// block = 128 thr (2 waves x 32 queries), KV chunk = 256 keys, tile = 32 keys.
// ---------------------------------------------------------------------------
#define OPITCH 132   // epilogue overlay pitch (66 words: bank-stride 2, free)

__global__ __launch_bounds__(128) void attn_kernel(
    const ushort* __restrict__ qg, const ushort* __restrict__ kg,
    const ushort* __restrict__ vtg, ushort* __restrict__ po,
    float* __restrict__ pm, float* __restrict__ pl)
{
    __shared__ ushort sO[64 * OPITCH];   // 16896 B, epilogue only

    const int tid = threadIdx.x;
    const int w = tid >> 6, lane = tid & 63;
    const int c = lane & 31, g = lane >> 5;

    // XCD-aware decomposition: keep all 16 q-tiles of one (bh,z) on one XCD
    const int flat = blockIdx.x;          // 0..2047
    const int xcd  = flat & 7;
    const int ii   = flat >> 3;           // 0..255
    const int pair = xcd * 16 + (ii & 15);// 0..127 = (z,bh)
    const int qt   = ii >> 4;             // 0..15
    const int bh   = pair & 31;
    const int z    = pair >> 5;

    const int q0 = qt * 64 + w * 32;
    const size_t bhoff = (size_t)bh * (N_ * D_);
    const int kt0 = z * (N_ / SPLIT);
    const float scale2 = 0.08838834764831845f * 1.44269504f;  // /sqrt(128)*log2e
    const float THR = 11.5f;

    short8 qf[8];
    const ushort* qrow = qg + bhoff + (size_t)(q0 + c) * D_;
#pragma unroll
    for (int ks = 0; ks < 8; ++ks)
        qf[ks] = *(const short8*)(qrow + ks * 16 + 8 * g);

    f32x16 oacc[4] = {};
    float m = -1e30f, l = 0.f;

    for (int t = 0; t < TPC; ++t) {
        const ushort* kp = kg + bhoff + (size_t)(kt0 + t * KT) * D_
                         + (size_t)c * D_ + 8 * g;       // lane's K row
        const ushort* vp = vtg + bhoff + kt0 + t * KT
                         + (size_t)c * N_ + 16 * 0 + 8 * g;  // lane's V row base

        // ---- S^T = K · Q^T  (two independent accumulator chains) ----
        f32x16 sacc0 = {}, sacc1 = {};
        __builtin_amdgcn_s_setprio(1);
#pragma unroll
        for (int ks = 0; ks < 4; ++ks) {
            short8 a0 = *(const short8*)(kp + (2 * ks) * 16);
            short8 a1 = *(const short8*)(kp + (2 * ks + 1) * 16);
            sacc0 = MFMA32(a0, qf[2 * ks], sacc0);
            sacc1 = MFMA32(a1, qf[2 * ks + 1], sacc1);
        }
        __builtin_amdgcn_s_setprio(0);

        // ---- online softmax (exp2 domain, defer-max) ----
        float p[16];
        float tmax = -1e30f;
#pragma unroll
        for (int r = 0; r < 16; ++r) {
            float s = (sacc0[r] + sacc1[r]) * scale2;
            p[r] = s;
            tmax = fmaxf(tmax, s);
        }
        tmax = fmaxf(tmax, __shfl_xor(tmax, 32, 64));
        if (!__all(tmax - m <= THR)) {
            const float mnew = fmaxf(m, tmax);
            const float corr = exp2f(m - mnew);
#pragma unroll
            for (int dt = 0; dt < 4; ++dt)
#pragma unroll
                for (int r = 0; r < 16; ++r) oacc[dt][r] *= corr;
            l *= corr;
            m = mnew;
        }
        float tsum = 0.f;
#pragma unroll
        for (int r = 0; r < 16; ++r) {
            p[r] = exp2f(p[r] - m);
            tsum += p[r];
        }
        tsum += __shfl_xor(tsum, 32, 64);
        l += tsum;

        uint pk[8];
#pragma unroll
        for (int pp = 0; pp < 8; ++pp)
            pk[pp] = f2b2(p[2 * pp], p[2 * pp + 1]);

        uint v0 = g ? pk[0] : pk[2];
        uint v1 = g ? pk[1] : pk[3];
        uint v2 = g ? pk[4] : pk[6];
        uint v3 = g ? pk[5] : pk[7];
        uint r0 = (uint)__shfl_xor((int)v0, 32, 64);
        uint r1 = (uint)__shfl_xor((int)v1, 32, 64);
        uint r2 = (uint)__shfl_xor((int)v2, 32, 64);
        uint r3 = (uint)__shfl_xor((int)v3, 32, 64);

        // ---- O^T += V^T · P^T  (V frags direct from global, [bh][d][n]) ----
        __builtin_amdgcn_s_setprio(1);
#pragma unroll
        for (int kb = 0; kb < 2; ++kb) {
            union { uint u[4]; short8 s; } pf;
            if (kb == 0) {
                pf.u[0] = g ? r0 : pk[0];
                pf.u[1] = g ? r1 : pk[1];
                pf.u[2] = g ? pk[2] : r0;
                pf.u[3] = g ? pk[3] : r1;
            } else {
                pf.u[0] = g ? r2 : pk[4];
                pf.u[1] = g ? r3 : pk[5];
                pf.u[2] = g ? pk[6] : r2;
                pf.u[3] = g ? pk[7] : r3;
            }
#pragma unroll
            for (int dt = 0; dt < 4; ++dt) {
                short8 a = *(const short8*)(vp + (size_t)(dt * 32) * N_ + kb * 16);
                oacc[dt] = MFMA32(a, pf.s, oacc[dt]);
            }
        }
        __builtin_amdgcn_s_setprio(0);
    }

    // ---- epilogue: LDS transpose -> coalesced bf16 partial-O write ----
    if (lane < 32) {
        pm[(size_t)(z * 32 + bh) * N_ + q0 + c] = m;
        pl[(size_t)(z * 32 + bh) * N_ + q0 + c] = l;
    }
    {
        const int qrl = w * 32 + c;
#pragma unroll
        for (int dt = 0; dt < 4; ++dt)
#pragma unroll
            for (int rg = 0; rg < 4; ++rg) {
                int d = dt * 32 + 8 * rg + 4 * g;
                uint2 pv = { f2b2(oacc[dt][4 * rg + 0], oacc[dt][4 * rg + 1]),
                             f2b2(oacc[dt][4 * rg + 2], oacc[dt][4 * rg + 3]) };
                *(uint2*)&sO[qrl * OPITCH + d] = pv;
            }
    }
    __syncthreads();
    {
        const size_t pbase = ((size_t)(z * 32 + bh) * N_ + qt * 64) * D_;
#pragma unroll
        for (int it = 0; it < 16; ++it) {
            int idx = it * 128 + tid;            // 0..2047 (8B granules)
            int r = idx >> 5, dgr = (idx & 31) * 4;
            uint2 v = *(const uint2*)&sO[r * OPITCH + dgr];
            *(uint2*)(po + pbase + (size_t)r * D_ + dgr) = v;
        }
    }
}

// ---------------------------------------------------------------------------
// Combine split-KV partials -> bf16 [b][n][A] (feeds FFN1 directly)
// ---------------------------------------------------------------------------
__global__ __launch_bounds__(256) void combine_kernel(
    const ushort* __restrict__ po, const float* __restrict__ pm,
    const float* __restrict__ pl, ushort* __restrict__ out)
{
    const int idx = blockIdx.x * 256 + threadIdx.x;
    const int row = idx >> 7, d = idx & 127;
    const int R = B_ * H_ * N_;  // 32768

    float ms[SPLIT];
    float M = -1e30f;
#pragma unroll
    for (int s = 0; s < SPLIT; ++s) {
        ms[s] = pm[(size_t)s * R + row];
        M = fmaxf(M, ms[s]);
    }
    float L = 0.f, acc = 0.f;
#pragma unroll
    for (int s = 0; s < SPLIT; ++s) {
        float wgt = exp2f(ms[s] - M);
        L += pl[(size_t)s * R + row] * wgt;
        acc += b2f(po[((size_t)s * R + row) * D_ + d]) * wgt;
    }
    const int bh = row >> 10, n = row & (N_ - 1);
    const int bb = bh >> 1, hh = bh & 1;
    out[((size_t)(bb * N_ + n)) * A_ + hh * D_ + d] = (ushort)f2b1(acc / L);
}

// ---------------------------------------------------------------------------
// step = LayerNorm(roll + prev)*g+b  -> fp32 (residual) + bf16 (GEMM A)
// ---------------------------------------------------------------------------
__global__ __launch_bounds__(256) void add_ln_kernel(
    const float* __restrict__ roll, const float* __restrict__ prev,
    const float* __restrict__ g, const float* __restrict__ bta,
    float* __restrict__ out, ushort* __restrict__ outb)
{
    const int row = blockIdx.x, tid = threadIdx.x;
    float v = roll[(size_t)row * A_ + tid] + prev[(size_t)row * A_ + tid];
    float s = v, s2 = v * v;
#pragma unroll
    for (int o = 32; o > 0; o >>= 1) {
        s  += __shfl_down(s, o, 64);
        s2 += __shfl_down(s2, o, 64);
    }
    __shared__ float ps[4], ps2[4];
    __shared__ float mu_s, rsig_s;
    const int wid = tid >> 6, lane = tid & 63;
    if (lane == 0) { ps[wid] = s; ps2[wid] = s2; }
    __syncthreads();
    if (tid == 0) {
        float S  = ps[0] + ps[1] + ps[2] + ps[3];
        float S2 = ps2[0] + ps2[1] + ps2[2] + ps2[3];
        float mu = S / A_;
        float var = S2 / A_ - mu * mu;
        mu_s = mu;
        rsig_s = rsqrtf(var + EPS_);
    }
    __syncthreads();
    float y = (v - mu_s) * rsig_s * g[tid] + bta[tid];
    out[(size_t)row * A_ + tid] = y;
    outb[(size_t)row * A_ + tid] = (ushort)f2b1(y);
}

// ---------------------------------------------------------------------------
__global__ __launch_bounds__(256) void pool_kernel(
    const float* __restrict__ ent, float* __restrict__ part)
{
    const int b = blockIdx.x, s = blockIdx.y, a = threadIdx.x;
    float acc = 0.f;
    for (int n = s * 32; n < s * 32 + 32; ++n)
        acc += ent[((size_t)b * N_ + n) * A_ + a];
    part[((size_t)b * 32 + s) * A_ + a] = acc;
}

__global__ __launch_bounds__(256) void final_kernel(
    const float* __restrict__ part, const float* __restrict__ We,
    const float* __restrict__ be, float* __restrict__ out)
{
    __shared__ float sp[A_];
    const int b = blockIdx.x, tid = threadIdx.x;
    float s = 0.f;
    for (int j = 0; j < 32; ++j) s += part[((size_t)b * 32 + j) * A_ + tid];
    sp[tid] = s * (1.0f / N_);
    __syncthreads();
    float acc = be[tid];
    for (int kk = 0; kk < A_; ++kk) acc += sp[kk] * We[(size_t)kk * A_ + tid];
    out[b * A_ + tid] = fmaxf(acc, 0.f);
}

// ---------------------------------------------------------------------------
extern "C" void kernel_launch(void* const* d_in, const int* in_sizes, int n_in,
                              void* d_out, int out_size, void* d_ws, size_t ws_size,
                              hipStream_t stream)
{
    const float* X    = (const float*)d_in[0];
    const float* Wq   = (const float*)d_in[1];
    const float* bq   = (const float*)d_in[2];
    const float* Wk   = (const float*)d_in[3];
    const float* bk   = (const float*)d_in[4];
    const float* Wv   = (const float*)d_in[5];
    const float* bv   = (const float*)d_in[6];
    const float* W1   = (const float*)d_in[7];
    const float* b1   = (const float*)d_in[8];
    const float* W2   = (const float*)d_in[9];
    const float* b2   = (const float*)d_in[10];
    const float* ln_g = (const float*)d_in[11];
    const float* ln_b = (const float*)d_in[12];
    const float* Wc   = (const float*)d_in[13];
    const float* bc   = (const float*)d_in[14];
    const float* We   = (const float*)d_in[15];
    const float* be   = (const float*)d_in[16];

    // ---- workspace layout (~107 MB) ----
    char* base = (char*)d_ws;
    ushort* qb     = (ushort*)base;  base += QKV_E * 2;   // q; attnb alias
    /* kb */                         base += QKV_E * 2;
    /* vt */                         base += QKV_E * 2;
    ushort* hbuf   = (ushort*)base;  base += (size_t)M_ * FFN_ * 2;  // aliases po/ent
    float*  attn   = (float*)base;   base += (size_t)M_ * A_ * 4;    // roll fp32
    float*  step   = (float*)base;   base += (size_t)M_ * A_ * 4;
    ushort* stepb  = (ushort*)base;  base += (size_t)M_ * A_ * 2;
    ushort* wqkv_t = (ushort*)base;  base += (size_t)3 * 3 * A_ * A_ * 2;
    ushort* w1_t   = (ushort*)base;  base += (size_t)3 * A_ * FFN_ * 2;
    ushort* w2_t   = (ushort*)base;  base += (size_t)3 * FFN_ * A_ * 2;
    ushort* wc_t   = (ushort*)base;  base += (size_t)A_ * A_ * 2;
    float*  part   = (float*)base;   base += (size_t)B_ * 32 * A_ * 4;
    float*  pm     = (float*)base;   base += (size_t)SPLIT * B_ * H_ * N_ * 4;
    float*  pl     = (float*)base;   base += (size_t)SPLIT * B_ * H_ * N_ * 4;
    ushort* kbuf   = qb + QKV_E;
    ushort* vtbuf  = qb + 2 * QKV_E;
    ushort* po     = hbuf;           // partial O: dead before FFN1 writes hbuf
    ushort* attnb  = qb;             // combine out: q dead after attn_kernel
    float*  ent    = (float*)hbuf;   // head output reuses hbuf

    // ---- weight/input prep ----
    transpose_qkv_kernel<<<dim3(8, 8, 9), 256, 0, stream>>>(Wq, Wk, Wv, wqkv_t);
    transpose_bf16_kernel<<<dim3(FFN_/32, A_/32, 3), 256, 0, stream>>>(
        W1, w1_t, A_, FFN_, (size_t)A_ * FFN_, (size_t)A_ * FFN_);
    transpose_bf16_kernel<<<dim3(A_/32, FFN_/32, 3), 256, 0, stream>>>(
        W2, w2_t, FFN_, A_, (size_t)FFN_ * A_, (size_t)FFN_ * A_);
    transpose_bf16_kernel<<<dim3(A_/32, A_/32, 1), 256, 0, stream>>>(
        Wc, wc_t, A_, A_, 0, 0);
    f32_to_bf16_kernel<<<(M_ * A_) / (256 * 8), 256, 0, stream>>>(X, stepb);

    const float* cur = X;   // fp32 residual input
    for (int i = 0; i < 3; ++i) {
        // fused QKV projection (A = stepb bf16)
        gemm_mfma<<<dim3(M_/128, 6), 256, 0, stream>>>(
            stepb, wqkv_t + (size_t)i * 3 * A_ * A_,
            bq + i * A_, bk + i * A_, bv + i * A_, qb, A_, 0, 5);

        attn_kernel<<<16 * SPLIT * B_ * H_, 128, 0, stream>>>(
            qb, kbuf, vtbuf, po, pm, pl);
        combine_kernel<<<(B_*H_*N_*D_)/256, 256, 0, stream>>>(po, pm, pl, attnb);

        gemm_mfma<<<dim3(M_/128, FFN_/128), 256, 0, stream>>>(
            attnb, w1_t + (size_t)i * A_ * FFN_, b1 + i * FFN_, nullptr, nullptr,
            hbuf, A_, FFN_, 2);
        gemm_mfma<<<dim3(M_/128, A_/128), 256, 0, stream>>>(
            hbuf, w2_t + (size_t)i * FFN_ * A_, b2 + i * A_, nullptr, nullptr,
            attn, FFN_, A_, 1);

        // writes step (fp32 residual) + stepb (bf16 A for next QKV / head)
        add_ln_kernel<<<M_, 256, 0, stream>>>(attn, cur, ln_g, ln_b, step, stepb);
        cur = step;
    }

    // head
    gemm_mfma<<<dim3(M_/128, A_/128), 256, 0, stream>>>(
        stepb, wc_t, bc, nullptr, nullptr, ent, A_, A_, 1);
    pool_kernel<<<dim3(B_, 32), 256, 0, stream>>>(ent, part);
    final_kernel<<<B_, 256, 0, stream>>>(part, We, be, (float*)d_out);
}

// Round 9
// 467.004 us; speedup vs baseline: 1.2988x; 1.1206x over previous
//
#include <hip/hip_runtime.h>
#include <hip/hip_bf16.h>
#include <cstddef>

#define B_   16
#define N_   1024
#define H_   2
#define D_   128
#define A_   256
#define FFN_ 1024
#define M_   (B_ * N_)   // 16384 rows
#define EPS_ 1e-5f
#define SPLIT 4
#define KT   32                    // keys per tile
#define TPC  (N_ / SPLIT / KT)     // tiles per chunk = 8
#define QKV_E ((size_t)B_ * H_ * N_ * D_)

typedef short  short8  __attribute__((ext_vector_type(8)));
typedef float  f32x16  __attribute__((ext_vector_type(16)));
typedef unsigned int uint;
typedef unsigned short ushort;

#define MFMA32(a, b, c) __builtin_amdgcn_mfma_f32_32x32x16_bf16(a, b, c, 0, 0, 0)

__device__ __forceinline__ uint f2b1(float x) {
    uint u = __float_as_uint(x);
    return (u + 0x7fffu + ((u >> 16) & 1u)) >> 16;
}
__device__ __forceinline__ uint f2b2(float lo, float hi) {
    return f2b1(lo) | (f2b1(hi) << 16);
}
__device__ __forceinline__ float b2f(ushort u) {
    return __uint_as_float(((uint)u) << 16);
}

// ---------------------------------------------------------------------------
// fp32 -> bf16 bulk convert (8 elems/thread)
// ---------------------------------------------------------------------------
__global__ __launch_bounds__(256) void f32_to_bf16_kernel(
    const float* __restrict__ in, ushort* __restrict__ out)
{
    const size_t i = ((size_t)blockIdx.x * 256 + threadIdx.x) * 8;
    float4 a = *(const float4*)(in + i);
    float4 b = *(const float4*)(in + i + 4);
    uint4 w = { f2b2(a.x, a.y), f2b2(a.z, a.w), f2b2(b.x, b.y), f2b2(b.z, b.w) };
    *(uint4*)(out + i) = w;
}

// ---------------------------------------------------------------------------
// Weight prep: W[K][N] fp32 -> Wt[N][K] bf16, blockIdx.z = layer (strided)
// ---------------------------------------------------------------------------
__global__ __launch_bounds__(256) void transpose_bf16_kernel(
    const float* __restrict__ W, ushort* __restrict__ Wt, int K, int N,
    size_t sstride, size_t dstride)
{
    __shared__ float tile[32][33];
    W  += (size_t)blockIdx.z * sstride;
    Wt += (size_t)blockIdx.z * dstride;
    const int n0 = blockIdx.x * 32, k0 = blockIdx.y * 32;
    const int tc = threadIdx.x & 31, tr = threadIdx.x >> 5;
#pragma unroll
    for (int it = 0; it < 4; ++it) {
        int r = it * 8 + tr;
        tile[r][tc] = W[(size_t)(k0 + r) * N + n0 + tc];
    }
    __syncthreads();
#pragma unroll
    for (int it = 0; it < 4; ++it) {
        int r = it * 8 + tr;
        Wt[(size_t)(n0 + r) * K + k0 + tc] = (ushort)f2b1(tile[tc][r]);
    }
}

// packed QKV transpose: z = layer*3 + sec
__global__ __launch_bounds__(256) void transpose_qkv_kernel(
    const float* __restrict__ Wq, const float* __restrict__ Wk,
    const float* __restrict__ Wv, ushort* __restrict__ dst)
{
    __shared__ float tile[32][33];
    const int layer = blockIdx.z / 3, sec = blockIdx.z % 3;
    const float* W = (sec == 0 ? Wq : sec == 1 ? Wk : Wv) + (size_t)layer * A_ * A_;
    ushort* out = dst + (size_t)layer * (3 * A_ * A_) + (size_t)sec * A_ * A_;
    const int n0 = blockIdx.x * 32, k0 = blockIdx.y * 32;
    const int tc = threadIdx.x & 31, tr = threadIdx.x >> 5;
#pragma unroll
    for (int it = 0; it < 4; ++it) {
        int r = it * 8 + tr;
        tile[r][tc] = W[(size_t)(k0 + r) * A_ + n0 + tc];
    }
    __syncthreads();
#pragma unroll
    for (int it = 0; it < 4; ++it) {
        int r = it * 8 + tr;
        out[(size_t)(n0 + r) * A_ + k0 + tc] = (ushort)f2b1(tile[tc][r]);
    }
}

// ---------------------------------------------------------------------------
// MFMA GEMM (R4-proven structure): reg-staged uint4 -> LDS pitch 72,
// single buffer, 2 barriers per K-chunk of 64.
// modes: 1 = relu fp32 (ldc)   2 = relu bf16 (ldc)
//        5 = fused QKV with FRAGMENT-MAJOR outputs:
//            Q/K: [bh][n/32][j=d/8][c=n%32][8]   (4096 ush per 32-key tile)
//            V:   [bh][n/32][dt=d/32][i=k/8][c=d%32][8]
//            -> every attn operand load is a coalesced 1KB wave load.
// ---------------------------------------------------------------------------
__global__ __launch_bounds__(256) void gemm_mfma(
    const ushort* __restrict__ Asrc, const ushort* __restrict__ Wt,
    const float* __restrict__ bias, const float* __restrict__ biasK,
    const float* __restrict__ biasV, void* __restrict__ outp,
    int K, int ldc, int mode)
{
    __shared__ ushort sA[128 * 72];
    __shared__ ushort sB[128 * 72];

    const int tid = threadIdx.x;
    const int wid = tid >> 6, lane = tid & 63;
    const int c = lane & 31, g = lane >> 5;
    const int wr = wid >> 1, wc = wid & 1;
    const int m0 = blockIdx.x * 128;
    const int n0 = blockIdx.y * 128;

    f32x16 acc[2][2] = {};

    for (int k0 = 0; k0 < K; k0 += 64) {
        __syncthreads();
#pragma unroll
        for (int it = 0; it < 4; ++it) {
            int idx = it * 256 + tid, r = idx >> 3, cc = (idx & 7) * 8;
            *(uint4*)&sA[r * 72 + cc] =
                *(const uint4*)(Asrc + (size_t)(m0 + r) * K + k0 + cc);
        }
#pragma unroll
        for (int it = 0; it < 4; ++it) {
            int idx = it * 256 + tid, r = idx >> 3, cc = (idx & 7) * 8;
            *(uint4*)&sB[r * 72 + cc] =
                *(const uint4*)(Wt + (size_t)(n0 + r) * K + k0 + cc);
        }
        __syncthreads();
#pragma unroll
        for (int ks = 0; ks < 4; ++ks) {
            const int ko = ks * 16 + 8 * g;
            short8 a0 = *(const short8*)&sA[(wr * 64 + c) * 72 + ko];
            short8 a1 = *(const short8*)&sA[(wr * 64 + 32 + c) * 72 + ko];
            short8 b0 = *(const short8*)&sB[(wc * 64 + c) * 72 + ko];
            short8 b1 = *(const short8*)&sB[(wc * 64 + 32 + c) * 72 + ko];
            acc[0][0] = MFMA32(a0, b0, acc[0][0]);
            acc[0][1] = MFMA32(a0, b1, acc[0][1]);
            acc[1][0] = MFMA32(a1, b0, acc[1][0]);
            acc[1][1] = MFMA32(a1, b1, acc[1][1]);
        }
    }

    const int sec = n0 >> 8;  // for mode 5 (block-uniform)
    const float* bp = bias;
    int nw = n0;
    if (mode == 5) {
        bp = (sec == 0 ? bias : sec == 1 ? biasK : biasV);
        nw = n0 & 255;
    }
    const float bz[2] = { bp[nw + wc * 64 + c], bp[nw + wc * 64 + 32 + c] };

#pragma unroll
    for (int mr = 0; mr < 2; ++mr) {
#pragma unroll
        for (int ct = 0; ct < 2; ++ct) {
            const int colbase = n0 + wc * 64 + ct * 32 + c;
#pragma unroll
            for (int rg = 0; rg < 4; ++rg) {
                const int row = m0 + wr * 64 + mr * 32 + 8 * rg + 4 * g;
                float v0 = acc[mr][ct][4 * rg + 0] + bz[ct];
                float v1 = acc[mr][ct][4 * rg + 1] + bz[ct];
                float v2 = acc[mr][ct][4 * rg + 2] + bz[ct];
                float v3 = acc[mr][ct][4 * rg + 3] + bz[ct];
                if (mode == 1 || mode == 2) {
                    v0 = fmaxf(v0, 0.f); v1 = fmaxf(v1, 0.f);
                    v2 = fmaxf(v2, 0.f); v3 = fmaxf(v3, 0.f);
                }
                if (mode == 1) {
                    float* o = (float*)outp;
                    o[(size_t)(row + 0) * ldc + colbase] = v0;
                    o[(size_t)(row + 1) * ldc + colbase] = v1;
                    o[(size_t)(row + 2) * ldc + colbase] = v2;
                    o[(size_t)(row + 3) * ldc + colbase] = v3;
                } else if (mode == 2) {
                    ushort* o = (ushort*)outp;
                    o[(size_t)(row + 0) * ldc + colbase] = (ushort)f2b1(v0);
                    o[(size_t)(row + 1) * ldc + colbase] = (ushort)f2b1(v1);
                    o[(size_t)(row + 2) * ldc + colbase] = (ushort)f2b1(v2);
                    o[(size_t)(row + 3) * ldc + colbase] = (ushort)f2b1(v3);
                } else {  // mode 5, fragment-major
                    const int cw = colbase & 255;
                    const int hh = cw >> 7, dd = cw & (D_ - 1);
                    if (sec < 2) {
                        // Q/K: ((bh*32 + n/32)*16 + d/8)*32*8 + (n%32)*8 + d%8
                        ushort* o = (ushort*)outp + (size_t)sec * QKV_E;
#pragma unroll
                        for (int r2 = 0; r2 < 4; ++r2) {
                            int rw = row + r2;
                            int bb = rw >> 10, np = rw & (N_ - 1);
                            float vv = (r2 == 0 ? v0 : r2 == 1 ? v1 : r2 == 2 ? v2 : v3);
                            size_t off = (((size_t)(bb * H_ + hh) * 32 + (np >> 5)) * 16
                                          + (dd >> 3)) * 256
                                         + (np & 31) * 8 + (dd & 7);
                            o[off] = (ushort)f2b1(vv);
                        }
                    } else {
                        // V: ((bh*32 + n/32)*4 + d/32)*4 + (n%32)/8 -> [d%32][n%8]
                        ushort* o = (ushort*)outp + 2 * QKV_E;
                        const int bb = row >> 10, np = row & (N_ - 1);
                        size_t off = ((((size_t)(bb * H_ + hh) * 32 + (np >> 5)) * 4
                                       + (dd >> 5)) * 4 + ((np & 31) >> 3)) * 256
                                     + (dd & 31) * 8 + (np & 7);
                        uint2 w = { f2b2(v0, v1), f2b2(v2, v3) };
                        *(uint2*)(o + off) = w;
                    }
                }
            }
        }
    }
}

// ---------------------------------------------------------------------------
// Flash attention, barrier-free, FRAGMENT-MAJOR operands: every K/V/Q load is
// a fully-coalesced 1KB wave load (lanes (c,g) read contiguous bytes).
// No LDS in main loop; LDS only for the coalescing O-transpose epilogue.
// block = 128 thr (2 waves x 32 queries), KV chunk = 256 keys, tile = 32 keys.
// ---------------------------------------------------------------------------
#define OPITCH 132   // epilogue overlay pitch (66 words: bank-stride 2, free)

__global__ __launch_bounds__(128) void attn_kernel(
    const ushort* __restrict__ qg, const ushort* __restrict__ kg,
    const ushort* __restrict__ vtg, ushort* __restrict__ po,
    float* __restrict__ pm, float* __restrict__ pl)
{
    __shared__ ushort sO[64 * OPITCH];   // 16896 B, epilogue only

    const int tid = threadIdx.x;
    const int w = tid >> 6, lane = tid & 63;
    const int c = lane & 31, g = lane >> 5;

    // XCD-aware decomposition: keep all 16 q-tiles of one (bh,z) on one XCD
    const int flat = blockIdx.x;          // 0..2047
    const int xcd  = flat & 7;
    const int ii   = flat >> 3;           // 0..255
    const int pair = xcd * 16 + (ii & 15);// 0..127 = (z,bh)
    const int qt   = ii >> 4;             // 0..15
    const int bh   = pair & 31;
    const int z    = pair >> 5;

    const int q0 = qt * 64 + w * 32;
    const float scale2 = 0.08838834764831845f * 1.44269504f;  // /sqrt(128)*log2e
    const float THR = 11.5f;
    const int lo8 = c * 8;                // lane offset within fragment row

    // Q fragments: QF[bh][q/32][j][c][8]
    short8 qf[8];
    const ushort* qt_ = qg + ((size_t)bh * 32 + (q0 >> 5)) * 4096;
#pragma unroll
    for (int ks = 0; ks < 8; ++ks)
        qf[ks] = *(const short8*)(qt_ + (2 * ks + g) * 256 + lo8);

    f32x16 oacc[4] = {};
    float m = -1e30f, l = 0.f;

    for (int t = 0; t < TPC; ++t) {
        const size_t tb = ((size_t)bh * 32 + z * 8 + t) * 4096;
        const ushort* kt_ = kg + tb;
        const ushort* vt_ = vtg + tb;

        // ---- S^T = K · Q^T  (two independent accumulator chains) ----
        f32x16 sacc0 = {}, sacc1 = {};
        __builtin_amdgcn_s_setprio(1);
#pragma unroll
        for (int ks = 0; ks < 4; ++ks) {
            short8 a0 = *(const short8*)(kt_ + (4 * ks + g) * 256 + lo8);
            short8 a1 = *(const short8*)(kt_ + (4 * ks + 2 + g) * 256 + lo8);
            sacc0 = MFMA32(a0, qf[2 * ks], sacc0);
            sacc1 = MFMA32(a1, qf[2 * ks + 1], sacc1);
        }
        __builtin_amdgcn_s_setprio(0);

        // ---- online softmax (exp2 domain, defer-max) ----
        float p[16];
        float tmax = -1e30f;
#pragma unroll
        for (int r = 0; r < 16; ++r) {
            float s = (sacc0[r] + sacc1[r]) * scale2;
            p[r] = s;
            tmax = fmaxf(tmax, s);
        }
        tmax = fmaxf(tmax, __shfl_xor(tmax, 32, 64));
        if (!__all(tmax - m <= THR)) {
            const float mnew = fmaxf(m, tmax);
            const float corr = exp2f(m - mnew);
#pragma unroll
            for (int dt = 0; dt < 4; ++dt)
#pragma unroll
                for (int r = 0; r < 16; ++r) oacc[dt][r] *= corr;
            l *= corr;
            m = mnew;
        }
        float tsum = 0.f;
#pragma unroll
        for (int r = 0; r < 16; ++r) {
            p[r] = exp2f(p[r] - m);
            tsum += p[r];
        }
        tsum += __shfl_xor(tsum, 32, 64);
        l += tsum;

        uint pk[8];
#pragma unroll
        for (int pp = 0; pp < 8; ++pp)
            pk[pp] = f2b2(p[2 * pp], p[2 * pp + 1]);

        uint v0 = g ? pk[0] : pk[2];
        uint v1 = g ? pk[1] : pk[3];
        uint v2 = g ? pk[4] : pk[6];
        uint v3 = g ? pk[5] : pk[7];
        uint r0 = (uint)__shfl_xor((int)v0, 32, 64);
        uint r1 = (uint)__shfl_xor((int)v1, 32, 64);
        uint r2 = (uint)__shfl_xor((int)v2, 32, 64);
        uint r3 = (uint)__shfl_xor((int)v3, 32, 64);

        // ---- O^T += V^T · P^T  (VF[bh][kt][dt][i][c][8]) ----
        __builtin_amdgcn_s_setprio(1);
#pragma unroll
        for (int kb = 0; kb < 2; ++kb) {
            union { uint u[4]; short8 s; } pf;
            if (kb == 0) {
                pf.u[0] = g ? r0 : pk[0];
                pf.u[1] = g ? r1 : pk[1];
                pf.u[2] = g ? pk[2] : r0;
                pf.u[3] = g ? pk[3] : r1;
            } else {
                pf.u[0] = g ? r2 : pk[4];
                pf.u[1] = g ? r3 : pk[5];
                pf.u[2] = g ? pk[6] : r2;
                pf.u[3] = g ? pk[7] : r3;
            }
#pragma unroll
            for (int dt = 0; dt < 4; ++dt) {
                short8 a = *(const short8*)(vt_ + dt * 1024 + kb * 512 + g * 256 + lo8);
                oacc[dt] = MFMA32(a, pf.s, oacc[dt]);
            }
        }
        __builtin_amdgcn_s_setprio(0);
    }

    // ---- epilogue: LDS transpose -> coalesced bf16 partial-O write ----
    if (lane < 32) {
        pm[(size_t)(z * 32 + bh) * N_ + q0 + c] = m;
        pl[(size_t)(z * 32 + bh) * N_ + q0 + c] = l;
    }
    {
        const int qrl = w * 32 + c;
#pragma unroll
        for (int dt = 0; dt < 4; ++dt)
#pragma unroll
            for (int rg = 0; rg < 4; ++rg) {
                int d = dt * 32 + 8 * rg + 4 * g;
                uint2 pv = { f2b2(oacc[dt][4 * rg + 0], oacc[dt][4 * rg + 1]),
                             f2b2(oacc[dt][4 * rg + 2], oacc[dt][4 * rg + 3]) };
                *(uint2*)&sO[qrl * OPITCH + d] = pv;
            }
    }
    __syncthreads();
    {
        const size_t pbase = ((size_t)(z * 32 + bh) * N_ + qt * 64) * D_;
#pragma unroll
        for (int it = 0; it < 16; ++it) {
            int idx = it * 128 + tid;            // 0..2047 (8B granules)
            int r = idx >> 5, dgr = (idx & 31) * 4;
            uint2 v = *(const uint2*)&sO[r * OPITCH + dgr];
            *(uint2*)(po + pbase + (size_t)r * D_ + dgr) = v;
        }
    }
}

// ---------------------------------------------------------------------------
// Combine split-KV partials -> bf16 [b][n][A] (feeds FFN1 directly)
// ---------------------------------------------------------------------------
__global__ __launch_bounds__(256) void combine_kernel(
    const ushort* __restrict__ po, const float* __restrict__ pm,
    const float* __restrict__ pl, ushort* __restrict__ out)
{
    const int idx = blockIdx.x * 256 + threadIdx.x;
    const int row = idx >> 7, d = idx & 127;
    const int R = B_ * H_ * N_;  // 32768

    float ms[SPLIT];
    float M = -1e30f;
#pragma unroll
    for (int s = 0; s < SPLIT; ++s) {
        ms[s] = pm[(size_t)s * R + row];
        M = fmaxf(M, ms[s]);
    }
    float L = 0.f, acc = 0.f;
#pragma unroll
    for (int s = 0; s < SPLIT; ++s) {
        float wgt = exp2f(ms[s] - M);
        L += pl[(size_t)s * R + row] * wgt;
        acc += b2f(po[((size_t)s * R + row) * D_ + d]) * wgt;
    }
    const int bh = row >> 10, n = row & (N_ - 1);
    const int bb = bh >> 1, hh = bh & 1;
    out[((size_t)(bb * N_ + n)) * A_ + hh * D_ + d] = (ushort)f2b1(acc / L);
}

// ---------------------------------------------------------------------------
// step = LayerNorm(roll + prev)*g+b  -> fp32 (residual) + bf16 (GEMM A)
// ---------------------------------------------------------------------------
__global__ __launch_bounds__(256) void add_ln_kernel(
    const float* __restrict__ roll, const float* __restrict__ prev,
    const float* __restrict__ g, const float* __restrict__ bta,
    float* __restrict__ out, ushort* __restrict__ outb)
{
    const int row = blockIdx.x, tid = threadIdx.x;
    float v = roll[(size_t)row * A_ + tid] + prev[(size_t)row * A_ + tid];
    float s = v, s2 = v * v;
#pragma unroll
    for (int o = 32; o > 0; o >>= 1) {
        s  += __shfl_down(s, o, 64);
        s2 += __shfl_down(s2, o, 64);
    }
    __shared__ float ps[4], ps2[4];
    __shared__ float mu_s, rsig_s;
    const int wid = tid >> 6, lane = tid & 63;
    if (lane == 0) { ps[wid] = s; ps2[wid] = s2; }
    __syncthreads();
    if (tid == 0) {
        float S  = ps[0] + ps[1] + ps[2] + ps[3];
        float S2 = ps2[0] + ps2[1] + ps2[2] + ps2[3];
        float mu = S / A_;
        float var = S2 / A_ - mu * mu;
        mu_s = mu;
        rsig_s = rsqrtf(var + EPS_);
    }
    __syncthreads();
    float y = (v - mu_s) * rsig_s * g[tid] + bta[tid];
    out[(size_t)row * A_ + tid] = y;
    outb[(size_t)row * A_ + tid] = (ushort)f2b1(y);
}

// ---------------------------------------------------------------------------
__global__ __launch_bounds__(256) void pool_kernel(
    const float* __restrict__ ent, float* __restrict__ part)
{
    const int b = blockIdx.x, s = blockIdx.y, a = threadIdx.x;
    float acc = 0.f;
    for (int n = s * 32; n < s * 32 + 32; ++n)
        acc += ent[((size_t)b * N_ + n) * A_ + a];
    part[((size_t)b * 32 + s) * A_ + a] = acc;
}

__global__ __launch_bounds__(256) void final_kernel(
    const float* __restrict__ part, const float* __restrict__ We,
    const float* __restrict__ be, float* __restrict__ out)
{
    __shared__ float sp[A_];
    const int b = blockIdx.x, tid = threadIdx.x;
    float s = 0.f;
    for (int j = 0; j < 32; ++j) s += part[((size_t)b * 32 + j) * A_ + tid];
    sp[tid] = s * (1.0f / N_);
    __syncthreads();
    float acc = be[tid];
    for (int kk = 0; kk < A_; ++kk) acc += sp[kk] * We[(size_t)kk * A_ + tid];
    out[b * A_ + tid] = fmaxf(acc, 0.f);
}

// ---------------------------------------------------------------------------
extern "C" void kernel_launch(void* const* d_in, const int* in_sizes, int n_in,
                              void* d_out, int out_size, void* d_ws, size_t ws_size,
                              hipStream_t stream)
{
    const float* X    = (const float*)d_in[0];
    const float* Wq   = (const float*)d_in[1];
    const float* bq   = (const float*)d_in[2];
    const float* Wk   = (const float*)d_in[3];
    const float* bk   = (const float*)d_in[4];
    const float* Wv   = (const float*)d_in[5];
    const float* bv   = (const float*)d_in[6];
    const float* W1   = (const float*)d_in[7];
    const float* b1   = (const float*)d_in[8];
    const float* W2   = (const float*)d_in[9];
    const float* b2   = (const float*)d_in[10];
    const float* ln_g = (const float*)d_in[11];
    const float* ln_b = (const float*)d_in[12];
    const float* Wc   = (const float*)d_in[13];
    const float* bc   = (const float*)d_in[14];
    const float* We   = (const float*)d_in[15];
    const float* be   = (const float*)d_in[16];

    // ---- workspace layout (~107 MB) ----
    char* base = (char*)d_ws;
    ushort* qb     = (ushort*)base;  base += QKV_E * 2;   // q; attnb alias
    /* kb */                         base += QKV_E * 2;
    /* vt */                         base += QKV_E * 2;
    ushort* hbuf   = (ushort*)base;  base += (size_t)M_ * FFN_ * 2;  // aliases po/ent
    float*  attn   = (float*)base;   base += (size_t)M_ * A_ * 4;    // roll fp32
    float*  step   = (float*)base;   base += (size_t)M_ * A_ * 4;
    ushort* stepb  = (ushort*)base;  base += (size_t)M_ * A_ * 2;
    ushort* wqkv_t = (ushort*)base;  base += (size_t)3 * 3 * A_ * A_ * 2;
    ushort* w1_t   = (ushort*)base;  base += (size_t)3 * A_ * FFN_ * 2;
    ushort* w2_t   = (ushort*)base;  base += (size_t)3 * FFN_ * A_ * 2;
    ushort* wc_t   = (ushort*)base;  base += (size_t)A_ * A_ * 2;
    float*  part   = (float*)base;   base += (size_t)B_ * 32 * A_ * 4;
    float*  pm     = (float*)base;   base += (size_t)SPLIT * B_ * H_ * N_ * 4;
    float*  pl     = (float*)base;   base += (size_t)SPLIT * B_ * H_ * N_ * 4;
    ushort* kbuf   = qb + QKV_E;
    ushort* vtbuf  = qb + 2 * QKV_E;
    ushort* po     = hbuf;           // partial O: dead before FFN1 writes hbuf
    ushort* attnb  = qb;             // combine out: q dead after attn_kernel
    float*  ent    = (float*)hbuf;   // head output reuses hbuf

    // ---- weight/input prep ----
    transpose_qkv_kernel<<<dim3(8, 8, 9), 256, 0, stream>>>(Wq, Wk, Wv, wqkv_t);
    transpose_bf16_kernel<<<dim3(FFN_/32, A_/32, 3), 256, 0, stream>>>(
        W1, w1_t, A_, FFN_, (size_t)A_ * FFN_, (size_t)A_ * FFN_);
    transpose_bf16_kernel<<<dim3(A_/32, FFN_/32, 3), 256, 0, stream>>>(
        W2, w2_t, FFN_, A_, (size_t)FFN_ * A_, (size_t)FFN_ * A_);
    transpose_bf16_kernel<<<dim3(A_/32, A_/32, 1), 256, 0, stream>>>(
        Wc, wc_t, A_, A_, 0, 0);
    f32_to_bf16_kernel<<<(M_ * A_) / (256 * 8), 256, 0, stream>>>(X, stepb);

    const float* cur = X;   // fp32 residual input
    for (int i = 0; i < 3; ++i) {
        // fused QKV projection (A = stepb bf16), fragment-major outputs
        gemm_mfma<<<dim3(M_/128, 6), 256, 0, stream>>>(
            stepb, wqkv_t + (size_t)i * 3 * A_ * A_,
            bq + i * A_, bk + i * A_, bv + i * A_, qb, A_, 0, 5);

        attn_kernel<<<16 * SPLIT * B_ * H_, 128, 0, stream>>>(
            qb, kbuf, vtbuf, po, pm, pl);
        combine_kernel<<<(B_*H_*N_*D_)/256, 256, 0, stream>>>(po, pm, pl, attnb);

        gemm_mfma<<<dim3(M_/128, FFN_/128), 256, 0, stream>>>(
            attnb, w1_t + (size_t)i * A_ * FFN_, b1 + i * FFN_, nullptr, nullptr,
            hbuf, A_, FFN_, 2);
        gemm_mfma<<<dim3(M_/128, A_/128), 256, 0, stream>>>(
            hbuf, w2_t + (size_t)i * FFN_ * A_, b2 + i * A_, nullptr, nullptr,
            attn, FFN_, A_, 1);

        // writes step (fp32 residual) + stepb (bf16 A for next QKV / head)
        add_ln_kernel<<<M_, 256, 0, stream>>>(attn, cur, ln_g, ln_b, step, stepb);
        cur = step;
    }

    // head
    gemm_mfma<<<dim3(M_/128, A_/128), 256, 0, stream>>>(
        stepb, wc_t, bc, nullptr, nullptr, ent, A_, A_, 1);
    pool_kernel<<<dim3(B_, 32), 256, 0, stream>>>(ent, part);
    final_kernel<<<B_, 256, 0, stream>>>(part, We, be, (float*)d_out);
}

// Round 10
// 425.036 us; speedup vs baseline: 1.4271x; 1.0987x over previous
//
#include <hip/hip_runtime.h>
#include <hip/hip_bf16.h>
#include <cstddef>

#define B_   16
#define N_   1024
#define H_   2
#define D_   128
#define A_   256
#define FFN_ 1024
#define M_   (B_ * N_)   // 16384 rows
#define EPS_ 1e-5f
#define SPLIT 4
#define KT   32                    // keys per tile
#define TPC  (N_ / SPLIT / KT)     // tiles per chunk = 8
#define QKV_E ((size_t)B_ * H_ * N_ * D_)

typedef short  short8  __attribute__((ext_vector_type(8)));
typedef float  f32x16  __attribute__((ext_vector_type(16)));
typedef unsigned int uint;
typedef unsigned short ushort;

#define MFMA32(a, b, c) __builtin_amdgcn_mfma_f32_32x32x16_bf16(a, b, c, 0, 0, 0)

__device__ __forceinline__ uint f2b1(float x) {
    uint u = __float_as_uint(x);
    return (u + 0x7fffu + ((u >> 16) & 1u)) >> 16;
}
__device__ __forceinline__ uint f2b2(float lo, float hi) {
    return f2b1(lo) | (f2b1(hi) << 16);
}
__device__ __forceinline__ float b2f(ushort u) {
    return __uint_as_float(((uint)u) << 16);
}

// ---------------------------------------------------------------------------
// fp32 -> bf16 bulk convert (8 elems/thread)
// ---------------------------------------------------------------------------
__global__ __launch_bounds__(256) void f32_to_bf16_kernel(
    const float* __restrict__ in, ushort* __restrict__ out)
{
    const size_t i = ((size_t)blockIdx.x * 256 + threadIdx.x) * 8;
    float4 a = *(const float4*)(in + i);
    float4 b = *(const float4*)(in + i + 4);
    uint4 w = { f2b2(a.x, a.y), f2b2(a.z, a.w), f2b2(b.x, b.y), f2b2(b.z, b.w) };
    *(uint4*)(out + i) = w;
}

// ---------------------------------------------------------------------------
// Weight prep: W[K][N] fp32 -> Wt[N][K] bf16, blockIdx.z = layer (strided)
// ---------------------------------------------------------------------------
__global__ __launch_bounds__(256) void transpose_bf16_kernel(
    const float* __restrict__ W, ushort* __restrict__ Wt, int K, int N,
    size_t sstride, size_t dstride)
{
    __shared__ float tile[32][33];
    W  += (size_t)blockIdx.z * sstride;
    Wt += (size_t)blockIdx.z * dstride;
    const int n0 = blockIdx.x * 32, k0 = blockIdx.y * 32;
    const int tc = threadIdx.x & 31, tr = threadIdx.x >> 5;
#pragma unroll
    for (int it = 0; it < 4; ++it) {
        int r = it * 8 + tr;
        tile[r][tc] = W[(size_t)(k0 + r) * N + n0 + tc];
    }
    __syncthreads();
#pragma unroll
    for (int it = 0; it < 4; ++it) {
        int r = it * 8 + tr;
        Wt[(size_t)(n0 + r) * K + k0 + tc] = (ushort)f2b1(tile[tc][r]);
    }
}

// packed QKV transpose: z = layer*3 + sec
__global__ __launch_bounds__(256) void transpose_qkv_kernel(
    const float* __restrict__ Wq, const float* __restrict__ Wk,
    const float* __restrict__ Wv, ushort* __restrict__ dst)
{
    __shared__ float tile[32][33];
    const int layer = blockIdx.z / 3, sec = blockIdx.z % 3;
    const float* W = (sec == 0 ? Wq : sec == 1 ? Wk : Wv) + (size_t)layer * A_ * A_;
    ushort* out = dst + (size_t)layer * (3 * A_ * A_) + (size_t)sec * A_ * A_;
    const int n0 = blockIdx.x * 32, k0 = blockIdx.y * 32;
    const int tc = threadIdx.x & 31, tr = threadIdx.x >> 5;
#pragma unroll
    for (int it = 0; it < 4; ++it) {
        int r = it * 8 + tr;
        tile[r][tc] = W[(size_t)(k0 + r) * A_ + n0 + tc];
    }
    __syncthreads();
#pragma unroll
    for (int it = 0; it < 4; ++it) {
        int r = it * 8 + tr;
        out[(size_t)(n0 + r) * A_ + k0 + tc] = (ushort)f2b1(tile[tc][r]);
    }
}

// ---------------------------------------------------------------------------
// MFMA GEMM (R4-proven structure): reg-staged uint4 -> LDS pitch 72,
// single buffer, 2 barriers per K-chunk of 64.
// modes: 1 = relu fp32 (ldc)   2 = relu bf16 (ldc)
//        5 = fused QKV with FRAGMENT-MAJOR outputs:
//            Q/K: [bh][n/32][j=d/8][c=n%32][8]
//            V:   [bh][n/32][dt=d/32][i=k/8][c=d%32][8]
// ---------------------------------------------------------------------------
__global__ __launch_bounds__(256) void gemm_mfma(
    const ushort* __restrict__ Asrc, const ushort* __restrict__ Wt,
    const float* __restrict__ bias, const float* __restrict__ biasK,
    const float* __restrict__ biasV, void* __restrict__ outp,
    int K, int ldc, int mode)
{
    __shared__ ushort sA[128 * 72];
    __shared__ ushort sB[128 * 72];

    const int tid = threadIdx.x;
    const int wid = tid >> 6, lane = tid & 63;
    const int c = lane & 31, g = lane >> 5;
    const int wr = wid >> 1, wc = wid & 1;
    const int m0 = blockIdx.x * 128;
    const int n0 = blockIdx.y * 128;

    f32x16 acc[2][2] = {};

    for (int k0 = 0; k0 < K; k0 += 64) {
        __syncthreads();
#pragma unroll
        for (int it = 0; it < 4; ++it) {
            int idx = it * 256 + tid, r = idx >> 3, cc = (idx & 7) * 8;
            *(uint4*)&sA[r * 72 + cc] =
                *(const uint4*)(Asrc + (size_t)(m0 + r) * K + k0 + cc);
        }
#pragma unroll
        for (int it = 0; it < 4; ++it) {
            int idx = it * 256 + tid, r = idx >> 3, cc = (idx & 7) * 8;
            *(uint4*)&sB[r * 72 + cc] =
                *(const uint4*)(Wt + (size_t)(n0 + r) * K + k0 + cc);
        }
        __syncthreads();
#pragma unroll
        for (int ks = 0; ks < 4; ++ks) {
            const int ko = ks * 16 + 8 * g;
            short8 a0 = *(const short8*)&sA[(wr * 64 + c) * 72 + ko];
            short8 a1 = *(const short8*)&sA[(wr * 64 + 32 + c) * 72 + ko];
            short8 b0 = *(const short8*)&sB[(wc * 64 + c) * 72 + ko];
            short8 b1 = *(const short8*)&sB[(wc * 64 + 32 + c) * 72 + ko];
            acc[0][0] = MFMA32(a0, b0, acc[0][0]);
            acc[0][1] = MFMA32(a0, b1, acc[0][1]);
            acc[1][0] = MFMA32(a1, b0, acc[1][0]);
            acc[1][1] = MFMA32(a1, b1, acc[1][1]);
        }
    }

    const int sec = n0 >> 8;  // for mode 5 (block-uniform)
    const float* bp = bias;
    int nw = n0;
    if (mode == 5) {
        bp = (sec == 0 ? bias : sec == 1 ? biasK : biasV);
        nw = n0 & 255;
    }
    const float bz[2] = { bp[nw + wc * 64 + c], bp[nw + wc * 64 + 32 + c] };

#pragma unroll
    for (int mr = 0; mr < 2; ++mr) {
#pragma unroll
        for (int ct = 0; ct < 2; ++ct) {
            const int colbase = n0 + wc * 64 + ct * 32 + c;
#pragma unroll
            for (int rg = 0; rg < 4; ++rg) {
                const int row = m0 + wr * 64 + mr * 32 + 8 * rg + 4 * g;
                float v0 = acc[mr][ct][4 * rg + 0] + bz[ct];
                float v1 = acc[mr][ct][4 * rg + 1] + bz[ct];
                float v2 = acc[mr][ct][4 * rg + 2] + bz[ct];
                float v3 = acc[mr][ct][4 * rg + 3] + bz[ct];
                if (mode == 1 || mode == 2) {
                    v0 = fmaxf(v0, 0.f); v1 = fmaxf(v1, 0.f);
                    v2 = fmaxf(v2, 0.f); v3 = fmaxf(v3, 0.f);
                }
                if (mode == 1) {
                    float* o = (float*)outp;
                    o[(size_t)(row + 0) * ldc + colbase] = v0;
                    o[(size_t)(row + 1) * ldc + colbase] = v1;
                    o[(size_t)(row + 2) * ldc + colbase] = v2;
                    o[(size_t)(row + 3) * ldc + colbase] = v3;
                } else if (mode == 2) {
                    ushort* o = (ushort*)outp;
                    o[(size_t)(row + 0) * ldc + colbase] = (ushort)f2b1(v0);
                    o[(size_t)(row + 1) * ldc + colbase] = (ushort)f2b1(v1);
                    o[(size_t)(row + 2) * ldc + colbase] = (ushort)f2b1(v2);
                    o[(size_t)(row + 3) * ldc + colbase] = (ushort)f2b1(v3);
                } else {  // mode 5, fragment-major
                    const int cw = colbase & 255;
                    const int hh = cw >> 7, dd = cw & (D_ - 1);
                    if (sec < 2) {
                        ushort* o = (ushort*)outp + (size_t)sec * QKV_E;
#pragma unroll
                        for (int r2 = 0; r2 < 4; ++r2) {
                            int rw = row + r2;
                            int bb = rw >> 10, np = rw & (N_ - 1);
                            float vv = (r2 == 0 ? v0 : r2 == 1 ? v1 : r2 == 2 ? v2 : v3);
                            size_t off = (((size_t)(bb * H_ + hh) * 32 + (np >> 5)) * 16
                                          + (dd >> 3)) * 256
                                         + (np & 31) * 8 + (dd & 7);
                            o[off] = (ushort)f2b1(vv);
                        }
                    } else {
                        ushort* o = (ushort*)outp + 2 * QKV_E;
                        const int bb = row >> 10, np = row & (N_ - 1);
                        size_t off = ((((size_t)(bb * H_ + hh) * 32 + (np >> 5)) * 4
                                       + (dd >> 5)) * 4 + ((np & 31) >> 3)) * 256
                                     + (dd & 31) * 8 + (np & 7);
                        uint2 w = { f2b2(v0, v1), f2b2(v2, v3) };
                        *(uint2*)(o + off) = w;
                    }
                }
            }
        }
    }
}

// ---------------------------------------------------------------------------
// Flash attention, barrier-free, fragment-major operands.
// R10: register diet — single S-accumulator chain (-16 VGPR) + forced
// 3 waves/SIMD via __launch_bounds__ (R9 was accumulator-pressure-bound at
// ~2 waves/SIMD: VGPR_Count=112 excludes the ~96 acc regs).
// ---------------------------------------------------------------------------
#define OPITCH 132   // epilogue overlay pitch (66 words: bank-stride 2, free)

__global__ __launch_bounds__(128, 3) void attn_kernel(
    const ushort* __restrict__ qg, const ushort* __restrict__ kg,
    const ushort* __restrict__ vtg, ushort* __restrict__ po,
    float* __restrict__ pm, float* __restrict__ pl)
{
    __shared__ ushort sO[64 * OPITCH];   // 16896 B, epilogue only

    const int tid = threadIdx.x;
    const int w = tid >> 6, lane = tid & 63;
    const int c = lane & 31, g = lane >> 5;

    // XCD-aware decomposition: keep all 16 q-tiles of one (bh,z) on one XCD
    const int flat = blockIdx.x;          // 0..2047
    const int xcd  = flat & 7;
    const int ii   = flat >> 3;           // 0..255
    const int pair = xcd * 16 + (ii & 15);// 0..127 = (z,bh)
    const int qt   = ii >> 4;             // 0..15
    const int bh   = pair & 31;
    const int z    = pair >> 5;

    const int q0 = qt * 64 + w * 32;
    const float scale2 = 0.08838834764831845f * 1.44269504f;  // /sqrt(128)*log2e
    const float THR = 11.5f;
    const int lo8 = c * 8;                // lane offset within fragment row

    // Q fragments: QF[bh][q/32][j][c][8]
    short8 qf[8];
    const ushort* qt_ = qg + ((size_t)bh * 32 + (q0 >> 5)) * 4096;
#pragma unroll
    for (int ks = 0; ks < 8; ++ks)
        qf[ks] = *(const short8*)(qt_ + (2 * ks + g) * 256 + lo8);

    f32x16 oacc[4] = {};
    float m = -1e30f, l = 0.f;

    for (int t = 0; t < TPC; ++t) {
        const size_t tb = ((size_t)bh * 32 + z * 8 + t) * 4096;
        const ushort* kt_ = kg + tb;
        const ushort* vt_ = vtg + tb;

        // ---- S^T = K · Q^T  (single accumulator chain: -16 VGPR) ----
        f32x16 sacc = {};
        __builtin_amdgcn_s_setprio(1);
#pragma unroll
        for (int ks = 0; ks < 8; ++ks) {
            short8 a = *(const short8*)(kt_ + (2 * ks + g) * 256 + lo8);
            sacc = MFMA32(a, qf[ks], sacc);
        }
        __builtin_amdgcn_s_setprio(0);

        // ---- online softmax (exp2 domain, defer-max) ----
        float p[16];
        float tmax = -1e30f;
#pragma unroll
        for (int r = 0; r < 16; ++r) {
            float s = sacc[r] * scale2;
            p[r] = s;
            tmax = fmaxf(tmax, s);
        }
        tmax = fmaxf(tmax, __shfl_xor(tmax, 32, 64));
        if (!__all(tmax - m <= THR)) {
            const float mnew = fmaxf(m, tmax);
            const float corr = exp2f(m - mnew);
#pragma unroll
            for (int dt = 0; dt < 4; ++dt)
#pragma unroll
                for (int r = 0; r < 16; ++r) oacc[dt][r] *= corr;
            l *= corr;
            m = mnew;
        }
        float tsum = 0.f;
#pragma unroll
        for (int r = 0; r < 16; ++r) {
            p[r] = exp2f(p[r] - m);
            tsum += p[r];
        }
        tsum += __shfl_xor(tsum, 32, 64);
        l += tsum;

        uint pk[8];
#pragma unroll
        for (int pp = 0; pp < 8; ++pp)
            pk[pp] = f2b2(p[2 * pp], p[2 * pp + 1]);

        uint v0 = g ? pk[0] : pk[2];
        uint v1 = g ? pk[1] : pk[3];
        uint v2 = g ? pk[4] : pk[6];
        uint v3 = g ? pk[5] : pk[7];
        uint r0 = (uint)__shfl_xor((int)v0, 32, 64);
        uint r1 = (uint)__shfl_xor((int)v1, 32, 64);
        uint r2 = (uint)__shfl_xor((int)v2, 32, 64);
        uint r3 = (uint)__shfl_xor((int)v3, 32, 64);

        // ---- O^T += V^T · P^T  (VF[bh][kt][dt][i][c][8]) ----
        __builtin_amdgcn_s_setprio(1);
#pragma unroll
        for (int kb = 0; kb < 2; ++kb) {
            union { uint u[4]; short8 s; } pf;
            if (kb == 0) {
                pf.u[0] = g ? r0 : pk[0];
                pf.u[1] = g ? r1 : pk[1];
                pf.u[2] = g ? pk[2] : r0;
                pf.u[3] = g ? pk[3] : r1;
            } else {
                pf.u[0] = g ? r2 : pk[4];
                pf.u[1] = g ? r3 : pk[5];
                pf.u[2] = g ? pk[6] : r2;
                pf.u[3] = g ? pk[7] : r3;
            }
#pragma unroll
            for (int dt = 0; dt < 4; ++dt) {
                short8 a = *(const short8*)(vt_ + dt * 1024 + kb * 512 + g * 256 + lo8);
                oacc[dt] = MFMA32(a, pf.s, oacc[dt]);
            }
        }
        __builtin_amdgcn_s_setprio(0);
    }

    // ---- epilogue: LDS transpose -> coalesced bf16 partial-O write ----
    if (lane < 32) {
        pm[(size_t)(z * 32 + bh) * N_ + q0 + c] = m;
        pl[(size_t)(z * 32 + bh) * N_ + q0 + c] = l;
    }
    {
        const int qrl = w * 32 + c;
#pragma unroll
        for (int dt = 0; dt < 4; ++dt)
#pragma unroll
            for (int rg = 0; rg < 4; ++rg) {
                int d = dt * 32 + 8 * rg + 4 * g;
                uint2 pv = { f2b2(oacc[dt][4 * rg + 0], oacc[dt][4 * rg + 1]),
                             f2b2(oacc[dt][4 * rg + 2], oacc[dt][4 * rg + 3]) };
                *(uint2*)&sO[qrl * OPITCH + d] = pv;
            }
    }
    __syncthreads();
    {
        const size_t pbase = ((size_t)(z * 32 + bh) * N_ + qt * 64) * D_;
#pragma unroll
        for (int it = 0; it < 16; ++it) {
            int idx = it * 128 + tid;            // 0..2047 (8B granules)
            int r = idx >> 5, dgr = (idx & 31) * 4;
            uint2 v = *(const uint2*)&sO[r * OPITCH + dgr];
            *(uint2*)(po + pbase + (size_t)r * D_ + dgr) = v;
        }
    }
}

// ---------------------------------------------------------------------------
// Combine split-KV partials -> bf16 [b][n][A] (feeds FFN1 directly)
// ---------------------------------------------------------------------------
__global__ __launch_bounds__(256) void combine_kernel(
    const ushort* __restrict__ po, const float* __restrict__ pm,
    const float* __restrict__ pl, ushort* __restrict__ out)
{
    const int idx = blockIdx.x * 256 + threadIdx.x;
    const int row = idx >> 7, d = idx & 127;
    const int R = B_ * H_ * N_;  // 32768

    float ms[SPLIT];
    float M = -1e30f;
#pragma unroll
    for (int s = 0; s < SPLIT; ++s) {
        ms[s] = pm[(size_t)s * R + row];
        M = fmaxf(M, ms[s]);
    }
    float L = 0.f, acc = 0.f;
#pragma unroll
    for (int s = 0; s < SPLIT; ++s) {
        float wgt = exp2f(ms[s] - M);
        L += pl[(size_t)s * R + row] * wgt;
        acc += b2f(po[((size_t)s * R + row) * D_ + d]) * wgt;
    }
    const int bh = row >> 10, n = row & (N_ - 1);
    const int bb = bh >> 1, hh = bh & 1;
    out[((size_t)(bb * N_ + n)) * A_ + hh * D_ + d] = (ushort)f2b1(acc / L);
}

// ---------------------------------------------------------------------------
// step = LayerNorm(roll(bf16) + prev)*g+b -> fp32 residual + bf16 GEMM A
// ---------------------------------------------------------------------------
__global__ __launch_bounds__(256) void add_ln_kernel(
    const ushort* __restrict__ roll, const float* __restrict__ prev,
    const float* __restrict__ g, const float* __restrict__ bta,
    float* __restrict__ out, ushort* __restrict__ outb)
{
    const int row = blockIdx.x, tid = threadIdx.x;
    float v = b2f(roll[(size_t)row * A_ + tid]) + prev[(size_t)row * A_ + tid];
    float s = v, s2 = v * v;
#pragma unroll
    for (int o = 32; o > 0; o >>= 1) {
        s  += __shfl_down(s, o, 64);
        s2 += __shfl_down(s2, o, 64);
    }
    __shared__ float ps[4], ps2[4];
    __shared__ float mu_s, rsig_s;
    const int wid = tid >> 6, lane = tid & 63;
    if (lane == 0) { ps[wid] = s; ps2[wid] = s2; }
    __syncthreads();
    if (tid == 0) {
        float S  = ps[0] + ps[1] + ps[2] + ps[3];
        float S2 = ps2[0] + ps2[1] + ps2[2] + ps2[3];
        float mu = S / A_;
        float var = S2 / A_ - mu * mu;
        mu_s = mu;
        rsig_s = rsqrtf(var + EPS_);
    }
    __syncthreads();
    float y = (v - mu_s) * rsig_s * g[tid] + bta[tid];
    out[(size_t)row * A_ + tid] = y;
    outb[(size_t)row * A_ + tid] = (ushort)f2b1(y);
}

// ---------------------------------------------------------------------------
__global__ __launch_bounds__(256) void pool_kernel(
    const ushort* __restrict__ ent, float* __restrict__ part)
{
    const int b = blockIdx.x, s = blockIdx.y, a = threadIdx.x;
    float acc = 0.f;
    for (int n = s * 32; n < s * 32 + 32; ++n)
        acc += b2f(ent[((size_t)b * N_ + n) * A_ + a]);
    part[((size_t)b * 32 + s) * A_ + a] = acc;
}

__global__ __launch_bounds__(256) void final_kernel(
    const float* __restrict__ part, const float* __restrict__ We,
    const float* __restrict__ be, float* __restrict__ out)
{
    __shared__ float sp[A_];
    const int b = blockIdx.x, tid = threadIdx.x;
    float s = 0.f;
    for (int j = 0; j < 32; ++j) s += part[((size_t)b * 32 + j) * A_ + tid];
    sp[tid] = s * (1.0f / N_);
    __syncthreads();
    float acc = be[tid];
    for (int kk = 0; kk < A_; ++kk) acc += sp[kk] * We[(size_t)kk * A_ + tid];
    out[b * A_ + tid] = fmaxf(acc, 0.f);
}

// ---------------------------------------------------------------------------
extern "C" void kernel_launch(void* const* d_in, const int* in_sizes, int n_in,
                              void* d_out, int out_size, void* d_ws, size_t ws_size,
                              hipStream_t stream)
{
    const float* X    = (const float*)d_in[0];
    const float* Wq   = (const float*)d_in[1];
    const float* bq   = (const float*)d_in[2];
    const float* Wk   = (const float*)d_in[3];
    const float* bk   = (const float*)d_in[4];
    const float* Wv   = (const float*)d_in[5];
    const float* bv   = (const float*)d_in[6];
    const float* W1   = (const float*)d_in[7];
    const float* b1   = (const float*)d_in[8];
    const float* W2   = (const float*)d_in[9];
    const float* b2   = (const float*)d_in[10];
    const float* ln_g = (const float*)d_in[11];
    const float* ln_b = (const float*)d_in[12];
    const float* Wc   = (const float*)d_in[13];
    const float* bc   = (const float*)d_in[14];
    const float* We   = (const float*)d_in[15];
    const float* be   = (const float*)d_in[16];

    // ---- workspace layout (~107 MB) ----
    char* base = (char*)d_ws;
    ushort* qb     = (ushort*)base;  base += QKV_E * 2;   // q; attnb alias
    /* kb */                         base += QKV_E * 2;
    /* vt */                         base += QKV_E * 2;
    ushort* hbuf   = (ushort*)base;  base += (size_t)M_ * FFN_ * 2;  // aliases po/ent
    ushort* rollb  = (ushort*)base;  base += (size_t)M_ * A_ * 2;    // FFN2 out bf16
    float*  step   = (float*)base;   base += (size_t)M_ * A_ * 4;
    ushort* stepb  = (ushort*)base;  base += (size_t)M_ * A_ * 2;
    ushort* wqkv_t = (ushort*)base;  base += (size_t)3 * 3 * A_ * A_ * 2;
    ushort* w1_t   = (ushort*)base;  base += (size_t)3 * A_ * FFN_ * 2;
    ushort* w2_t   = (ushort*)base;  base += (size_t)3 * FFN_ * A_ * 2;
    ushort* wc_t   = (ushort*)base;  base += (size_t)A_ * A_ * 2;
    float*  part   = (float*)base;   base += (size_t)B_ * 32 * A_ * 4;
    float*  pm     = (float*)base;   base += (size_t)SPLIT * B_ * H_ * N_ * 4;
    float*  pl     = (float*)base;   base += (size_t)SPLIT * B_ * H_ * N_ * 4;
    ushort* kbuf   = qb + QKV_E;
    ushort* vtbuf  = qb + 2 * QKV_E;
    ushort* po     = hbuf;           // partial O: dead before FFN1 writes hbuf
    ushort* attnb  = qb;             // combine out: q dead after attn_kernel
    ushort* ent    = hbuf;           // head output (bf16) reuses hbuf

    // ---- weight/input prep ----
    transpose_qkv_kernel<<<dim3(8, 8, 9), 256, 0, stream>>>(Wq, Wk, Wv, wqkv_t);
    transpose_bf16_kernel<<<dim3(FFN_/32, A_/32, 3), 256, 0, stream>>>(
        W1, w1_t, A_, FFN_, (size_t)A_ * FFN_, (size_t)A_ * FFN_);
    transpose_bf16_kernel<<<dim3(A_/32, FFN_/32, 3), 256, 0, stream>>>(
        W2, w2_t, FFN_, A_, (size_t)FFN_ * A_, (size_t)FFN_ * A_);
    transpose_bf16_kernel<<<dim3(A_/32, A_/32, 1), 256, 0, stream>>>(
        Wc, wc_t, A_, A_, 0, 0);
    f32_to_bf16_kernel<<<(M_ * A_) / (256 * 8), 256, 0, stream>>>(X, stepb);

    const float* cur = X;   // fp32 residual input
    for (int i = 0; i < 3; ++i) {
        // fused QKV projection (A = stepb bf16), fragment-major outputs
        gemm_mfma<<<dim3(M_/128, 6), 256, 0, stream>>>(
            stepb, wqkv_t + (size_t)i * 3 * A_ * A_,
            bq + i * A_, bk + i * A_, bv + i * A_, qb, A_, 0, 5);

        attn_kernel<<<16 * SPLIT * B_ * H_, 128, 0, stream>>>(
            qb, kbuf, vtbuf, po, pm, pl);
        combine_kernel<<<(B_*H_*N_*D_)/256, 256, 0, stream>>>(po, pm, pl, attnb);

        gemm_mfma<<<dim3(M_/128, FFN_/128), 256, 0, stream>>>(
            attnb, w1_t + (size_t)i * A_ * FFN_, b1 + i * FFN_, nullptr, nullptr,
            hbuf, A_, FFN_, 2);
        gemm_mfma<<<dim3(M_/128, A_/128), 256, 0, stream>>>(
            hbuf, w2_t + (size_t)i * FFN_ * A_, b2 + i * A_, nullptr, nullptr,
            rollb, FFN_, A_, 2);

        // writes step (fp32 residual) + stepb (bf16 A for next QKV / head)
        add_ln_kernel<<<M_, 256, 0, stream>>>(rollb, cur, ln_g, ln_b, step, stepb);
        cur = step;
    }

    // head (bf16 out -> pool)
    gemm_mfma<<<dim3(M_/128, A_/128), 256, 0, stream>>>(
        stepb, wc_t, bc, nullptr, nullptr, ent, A_, A_, 2);
    pool_kernel<<<dim3(B_, 32), 256, 0, stream>>>(ent, part);
    final_kernel<<<B_, 256, 0, stream>>>(part, We, be, (float*)d_out);
}

// Round 11
// 402.236 us; speedup vs baseline: 1.5079x; 1.0567x over previous
//
#include <hip/hip_runtime.h>
#include <hip/hip_bf16.h>
#include <cstddef>

#define B_   16
#define N_   1024
#define H_   2
#define D_   128
#define A_   256
#define FFN_ 1024
#define M_   (B_ * N_)   // 16384 rows
#define EPS_ 1e-5f
#define SPLIT 4
#define KT   32                    // keys per tile
#define TPC  (N_ / SPLIT / KT)     // tiles per chunk = 8
#define QKV_E ((size_t)B_ * H_ * N_ * D_)

typedef short  short8  __attribute__((ext_vector_type(8)));
typedef float  f32x16  __attribute__((ext_vector_type(16)));
typedef unsigned int uint;
typedef unsigned short ushort;

#define MFMA32(a, b, c) __builtin_amdgcn_mfma_f32_32x32x16_bf16(a, b, c, 0, 0, 0)

__device__ __forceinline__ uint f2b1(float x) {
    uint u = __float_as_uint(x);
    return (u + 0x7fffu + ((u >> 16) & 1u)) >> 16;
}
__device__ __forceinline__ uint f2b2(float lo, float hi) {
    return f2b1(lo) | (f2b1(hi) << 16);
}
__device__ __forceinline__ float b2f(ushort u) {
    return __uint_as_float(((uint)u) << 16);
}

// ---------------------------------------------------------------------------
// fp32 -> bf16 bulk convert (8 elems/thread)
// ---------------------------------------------------------------------------
__global__ __launch_bounds__(256) void f32_to_bf16_kernel(
    const float* __restrict__ in, ushort* __restrict__ out)
{
    const size_t i = ((size_t)blockIdx.x * 256 + threadIdx.x) * 8;
    float4 a = *(const float4*)(in + i);
    float4 b = *(const float4*)(in + i + 4);
    uint4 w = { f2b2(a.x, a.y), f2b2(a.z, a.w), f2b2(b.x, b.y), f2b2(b.z, b.w) };
    *(uint4*)(out + i) = w;
}

// ---------------------------------------------------------------------------
// Weight prep: W[K][N] fp32 -> Wt[N][K] bf16, blockIdx.z = layer (strided)
// ---------------------------------------------------------------------------
__global__ __launch_bounds__(256) void transpose_bf16_kernel(
    const float* __restrict__ W, ushort* __restrict__ Wt, int K, int N,
    size_t sstride, size_t dstride)
{
    __shared__ float tile[32][33];
    W  += (size_t)blockIdx.z * sstride;
    Wt += (size_t)blockIdx.z * dstride;
    const int n0 = blockIdx.x * 32, k0 = blockIdx.y * 32;
    const int tc = threadIdx.x & 31, tr = threadIdx.x >> 5;
#pragma unroll
    for (int it = 0; it < 4; ++it) {
        int r = it * 8 + tr;
        tile[r][tc] = W[(size_t)(k0 + r) * N + n0 + tc];
    }
    __syncthreads();
#pragma unroll
    for (int it = 0; it < 4; ++it) {
        int r = it * 8 + tr;
        Wt[(size_t)(n0 + r) * K + k0 + tc] = (ushort)f2b1(tile[tc][r]);
    }
}

// packed QKV transpose: z = layer*3 + sec
__global__ __launch_bounds__(256) void transpose_qkv_kernel(
    const float* __restrict__ Wq, const float* __restrict__ Wk,
    const float* __restrict__ Wv, ushort* __restrict__ dst)
{
    __shared__ float tile[32][33];
    const int layer = blockIdx.z / 3, sec = blockIdx.z % 3;
    const float* W = (sec == 0 ? Wq : sec == 1 ? Wk : Wv) + (size_t)layer * A_ * A_;
    ushort* out = dst + (size_t)layer * (3 * A_ * A_) + (size_t)sec * A_ * A_;
    const int n0 = blockIdx.x * 32, k0 = blockIdx.y * 32;
    const int tc = threadIdx.x & 31, tr = threadIdx.x >> 5;
#pragma unroll
    for (int it = 0; it < 4; ++it) {
        int r = it * 8 + tr;
        tile[r][tc] = W[(size_t)(k0 + r) * A_ + n0 + tc];
    }
    __syncthreads();
#pragma unroll
    for (int it = 0; it < 4; ++it) {
        int r = it * 8 + tr;
        out[(size_t)(n0 + r) * A_ + k0 + tc] = (ushort)f2b1(tile[tc][r]);
    }
}

// ---------------------------------------------------------------------------
// MFMA GEMM, templated row-tile: MR=2 -> BM=128 (wave 64x64), MR=1 -> BM=64
// (wave 32x64, LDS 27.6KB -> 5 blocks/CU: for skinny-N / big-K shapes).
// modes: 1 = relu fp32 (ldc)   2 = relu bf16 (ldc)
//        5 = fused QKV fragment-major   6 = relu + fused pool (atomicAdd)
// ---------------------------------------------------------------------------
template <int MR>
__global__ __launch_bounds__(256) void gemm_mfma(
    const ushort* __restrict__ Asrc, const ushort* __restrict__ Wt,
    const float* __restrict__ bias, const float* __restrict__ biasK,
    const float* __restrict__ biasV, void* __restrict__ outp,
    int K, int ldc, int mode)
{
    constexpr int BM = MR * 64;
    __shared__ ushort sA[BM * 72];
    __shared__ ushort sB[128 * 72];

    const int tid = threadIdx.x;
    const int wid = tid >> 6, lane = tid & 63;
    const int c = lane & 31, g = lane >> 5;
    const int wr = wid >> 1, wc = wid & 1;
    const int m0 = blockIdx.x * BM;
    const int n0 = blockIdx.y * 128;

    f32x16 acc[MR][2] = {};

    for (int k0 = 0; k0 < K; k0 += 64) {
        __syncthreads();
#pragma unroll
        for (int it = 0; it < BM / 32; ++it) {
            int idx = it * 256 + tid, r = idx >> 3, cc = (idx & 7) * 8;
            *(uint4*)&sA[r * 72 + cc] =
                *(const uint4*)(Asrc + (size_t)(m0 + r) * K + k0 + cc);
        }
#pragma unroll
        for (int it = 0; it < 4; ++it) {
            int idx = it * 256 + tid, r = idx >> 3, cc = (idx & 7) * 8;
            *(uint4*)&sB[r * 72 + cc] =
                *(const uint4*)(Wt + (size_t)(n0 + r) * K + k0 + cc);
        }
        __syncthreads();
#pragma unroll
        for (int ks = 0; ks < 4; ++ks) {
            const int ko = ks * 16 + 8 * g;
            short8 b0 = *(const short8*)&sB[(wc * 64 + c) * 72 + ko];
            short8 b1 = *(const short8*)&sB[(wc * 64 + 32 + c) * 72 + ko];
#pragma unroll
            for (int mr = 0; mr < MR; ++mr) {
                short8 a = *(const short8*)&sA[((wr * MR + mr) * 32 + c) * 72 + ko];
                acc[mr][0] = MFMA32(a, b0, acc[mr][0]);
                acc[mr][1] = MFMA32(a, b1, acc[mr][1]);
            }
        }
    }

    const int sec = n0 >> 8;  // for mode 5 (block-uniform)
    const float* bp = bias;
    int nw = n0;
    if (mode == 5) {
        bp = (sec == 0 ? bias : sec == 1 ? biasK : biasV);
        nw = n0 & 255;
    }
    const float bz[2] = { bp[nw + wc * 64 + c], bp[nw + wc * 64 + 32 + c] };

    float colsum[2] = { 0.f, 0.f };

#pragma unroll
    for (int mr = 0; mr < MR; ++mr) {
#pragma unroll
        for (int ct = 0; ct < 2; ++ct) {
            const int colbase = n0 + wc * 64 + ct * 32 + c;
#pragma unroll
            for (int rg = 0; rg < 4; ++rg) {
                const int row = m0 + (wr * MR + mr) * 32 + 8 * rg + 4 * g;
                float v0 = acc[mr][ct][4 * rg + 0] + bz[ct];
                float v1 = acc[mr][ct][4 * rg + 1] + bz[ct];
                float v2 = acc[mr][ct][4 * rg + 2] + bz[ct];
                float v3 = acc[mr][ct][4 * rg + 3] + bz[ct];
                if (mode == 1 || mode == 2 || mode == 6) {
                    v0 = fmaxf(v0, 0.f); v1 = fmaxf(v1, 0.f);
                    v2 = fmaxf(v2, 0.f); v3 = fmaxf(v3, 0.f);
                }
                if (mode == 1) {
                    float* o = (float*)outp;
                    o[(size_t)(row + 0) * ldc + colbase] = v0;
                    o[(size_t)(row + 1) * ldc + colbase] = v1;
                    o[(size_t)(row + 2) * ldc + colbase] = v2;
                    o[(size_t)(row + 3) * ldc + colbase] = v3;
                } else if (mode == 2) {
                    ushort* o = (ushort*)outp;
                    o[(size_t)(row + 0) * ldc + colbase] = (ushort)f2b1(v0);
                    o[(size_t)(row + 1) * ldc + colbase] = (ushort)f2b1(v1);
                    o[(size_t)(row + 2) * ldc + colbase] = (ushort)f2b1(v2);
                    o[(size_t)(row + 3) * ldc + colbase] = (ushort)f2b1(v3);
                } else if (mode == 6) {
                    colsum[ct] += v0 + v1 + v2 + v3;
                } else {  // mode 5, fragment-major
                    const int cw = colbase & 255;
                    const int hh = cw >> 7, dd = cw & (D_ - 1);
                    if (sec < 2) {
                        ushort* o = (ushort*)outp + (size_t)sec * QKV_E;
#pragma unroll
                        for (int r2 = 0; r2 < 4; ++r2) {
                            int rw = row + r2;
                            int bb = rw >> 10, np = rw & (N_ - 1);
                            float vv = (r2 == 0 ? v0 : r2 == 1 ? v1 : r2 == 2 ? v2 : v3);
                            size_t off = (((size_t)(bb * H_ + hh) * 32 + (np >> 5)) * 16
                                          + (dd >> 3)) * 256
                                         + (np & 31) * 8 + (dd & 7);
                            o[off] = (ushort)f2b1(vv);
                        }
                    } else {
                        ushort* o = (ushort*)outp + 2 * QKV_E;
                        const int bb = row >> 10, np = row & (N_ - 1);
                        size_t off = ((((size_t)(bb * H_ + hh) * 32 + (np >> 5)) * 4
                                       + (dd >> 5)) * 4 + ((np & 31) >> 3)) * 256
                                     + (dd & 31) * 8 + (np & 7);
                        uint2 w = { f2b2(v0, v1), f2b2(v2, v3) };
                        *(uint2*)(o + off) = w;
                    }
                }
            }
        }
    }

    if (mode == 6) {
        // lanes c and c+32 share a column -> one shfl_xor, then 32 atomics/wave
        float* part = (float*)outp;
        const int b = m0 >> 10;   // BM=64 divides 1024: block within one batch
#pragma unroll
        for (int ct = 0; ct < 2; ++ct) {
            float cs = colsum[ct] + __shfl_xor(colsum[ct], 32, 64);
            if (g == 0)
                atomicAdd(&part[(size_t)b * A_ + n0 + wc * 64 + ct * 32 + c], cs);
        }
    }
}

// ---------------------------------------------------------------------------
// Flash attention, barrier-free, fragment-major operands (R10-proven).
// ---------------------------------------------------------------------------
#define OPITCH 132   // epilogue overlay pitch (66 words: bank-stride 2, free)

__global__ __launch_bounds__(128, 3) void attn_kernel(
    const ushort* __restrict__ qg, const ushort* __restrict__ kg,
    const ushort* __restrict__ vtg, ushort* __restrict__ po,
    float* __restrict__ pm, float* __restrict__ pl)
{
    __shared__ ushort sO[64 * OPITCH];   // 16896 B, epilogue only

    const int tid = threadIdx.x;
    const int w = tid >> 6, lane = tid & 63;
    const int c = lane & 31, g = lane >> 5;

    const int flat = blockIdx.x;          // 0..2047
    const int xcd  = flat & 7;
    const int ii   = flat >> 3;           // 0..255
    const int pair = xcd * 16 + (ii & 15);// 0..127 = (z,bh)
    const int qt   = ii >> 4;             // 0..15
    const int bh   = pair & 31;
    const int z    = pair >> 5;

    const int q0 = qt * 64 + w * 32;
    const float scale2 = 0.08838834764831845f * 1.44269504f;  // /sqrt(128)*log2e
    const float THR = 11.5f;
    const int lo8 = c * 8;

    short8 qf[8];
    const ushort* qt_ = qg + ((size_t)bh * 32 + (q0 >> 5)) * 4096;
#pragma unroll
    for (int ks = 0; ks < 8; ++ks)
        qf[ks] = *(const short8*)(qt_ + (2 * ks + g) * 256 + lo8);

    f32x16 oacc[4] = {};
    float m = -1e30f, l = 0.f;

    for (int t = 0; t < TPC; ++t) {
        const size_t tb = ((size_t)bh * 32 + z * 8 + t) * 4096;
        const ushort* kt_ = kg + tb;
        const ushort* vt_ = vtg + tb;

        f32x16 sacc = {};
        __builtin_amdgcn_s_setprio(1);
#pragma unroll
        for (int ks = 0; ks < 8; ++ks) {
            short8 a = *(const short8*)(kt_ + (2 * ks + g) * 256 + lo8);
            sacc = MFMA32(a, qf[ks], sacc);
        }
        __builtin_amdgcn_s_setprio(0);

        float p[16];
        float tmax = -1e30f;
#pragma unroll
        for (int r = 0; r < 16; ++r) {
            float s = sacc[r] * scale2;
            p[r] = s;
            tmax = fmaxf(tmax, s);
        }
        tmax = fmaxf(tmax, __shfl_xor(tmax, 32, 64));
        if (!__all(tmax - m <= THR)) {
            const float mnew = fmaxf(m, tmax);
            const float corr = exp2f(m - mnew);
#pragma unroll
            for (int dt = 0; dt < 4; ++dt)
#pragma unroll
                for (int r = 0; r < 16; ++r) oacc[dt][r] *= corr;
            l *= corr;
            m = mnew;
        }
        float tsum = 0.f;
#pragma unroll
        for (int r = 0; r < 16; ++r) {
            p[r] = exp2f(p[r] - m);
            tsum += p[r];
        }
        tsum += __shfl_xor(tsum, 32, 64);
        l += tsum;

        uint pk[8];
#pragma unroll
        for (int pp = 0; pp < 8; ++pp)
            pk[pp] = f2b2(p[2 * pp], p[2 * pp + 1]);

        uint v0 = g ? pk[0] : pk[2];
        uint v1 = g ? pk[1] : pk[3];
        uint v2 = g ? pk[4] : pk[6];
        uint v3 = g ? pk[5] : pk[7];
        uint r0 = (uint)__shfl_xor((int)v0, 32, 64);
        uint r1 = (uint)__shfl_xor((int)v1, 32, 64);
        uint r2 = (uint)__shfl_xor((int)v2, 32, 64);
        uint r3 = (uint)__shfl_xor((int)v3, 32, 64);

        __builtin_amdgcn_s_setprio(1);
#pragma unroll
        for (int kb = 0; kb < 2; ++kb) {
            union { uint u[4]; short8 s; } pf;
            if (kb == 0) {
                pf.u[0] = g ? r0 : pk[0];
                pf.u[1] = g ? r1 : pk[1];
                pf.u[2] = g ? pk[2] : r0;
                pf.u[3] = g ? pk[3] : r1;
            } else {
                pf.u[0] = g ? r2 : pk[4];
                pf.u[1] = g ? r3 : pk[5];
                pf.u[2] = g ? pk[6] : r2;
                pf.u[3] = g ? pk[7] : r3;
            }
#pragma unroll
            for (int dt = 0; dt < 4; ++dt) {
                short8 a = *(const short8*)(vt_ + dt * 1024 + kb * 512 + g * 256 + lo8);
                oacc[dt] = MFMA32(a, pf.s, oacc[dt]);
            }
        }
        __builtin_amdgcn_s_setprio(0);
    }

    if (lane < 32) {
        pm[(size_t)(z * 32 + bh) * N_ + q0 + c] = m;
        pl[(size_t)(z * 32 + bh) * N_ + q0 + c] = l;
    }
    {
        const int qrl = w * 32 + c;
#pragma unroll
        for (int dt = 0; dt < 4; ++dt)
#pragma unroll
            for (int rg = 0; rg < 4; ++rg) {
                int d = dt * 32 + 8 * rg + 4 * g;
                uint2 pv = { f2b2(oacc[dt][4 * rg + 0], oacc[dt][4 * rg + 1]),
                             f2b2(oacc[dt][4 * rg + 2], oacc[dt][4 * rg + 3]) };
                *(uint2*)&sO[qrl * OPITCH + d] = pv;
            }
    }
    __syncthreads();
    {
        const size_t pbase = ((size_t)(z * 32 + bh) * N_ + qt * 64) * D_;
#pragma unroll
        for (int it = 0; it < 16; ++it) {
            int idx = it * 128 + tid;
            int r = idx >> 5, dgr = (idx & 31) * 4;
            uint2 v = *(const uint2*)&sO[r * OPITCH + dgr];
            *(uint2*)(po + pbase + (size_t)r * D_ + dgr) = v;
        }
    }
}

// ---------------------------------------------------------------------------
// Combine split-KV partials -> bf16 [b][n][A], 8 elems/thread (vectorized)
// ---------------------------------------------------------------------------
__global__ __launch_bounds__(256) void combine_kernel(
    const ushort* __restrict__ po, const float* __restrict__ pm,
    const float* __restrict__ pl, ushort* __restrict__ out)
{
    const int idx = blockIdx.x * 256 + threadIdx.x;   // 524288 granules
    const int row = idx >> 4, d0 = (idx & 15) * 8;
    const int R = B_ * H_ * N_;  // 32768

    float ms[SPLIT];
    float M = -1e30f;
#pragma unroll
    for (int s = 0; s < SPLIT; ++s) {
        ms[s] = pm[(size_t)s * R + row];
        M = fmaxf(M, ms[s]);
    }
    float L = 0.f;
    float acc[8] = {};
#pragma unroll
    for (int s = 0; s < SPLIT; ++s) {
        float wgt = exp2f(ms[s] - M);
        L += pl[(size_t)s * R + row] * wgt;
        uint4 pv = *(const uint4*)(po + ((size_t)s * R + row) * D_ + d0);
        const ushort* pu = (const ushort*)&pv;
#pragma unroll
        for (int j = 0; j < 8; ++j) acc[j] += b2f(pu[j]) * wgt;
    }
    const float inv = 1.f / L;
    uint4 w;
    w.x = f2b2(acc[0] * inv, acc[1] * inv);
    w.y = f2b2(acc[2] * inv, acc[3] * inv);
    w.z = f2b2(acc[4] * inv, acc[5] * inv);
    w.w = f2b2(acc[6] * inv, acc[7] * inv);
    const int bh = row >> 10, n = row & (N_ - 1);
    const int bb = bh >> 1, hh = bh & 1;
    *(uint4*)(out + ((size_t)(bb * N_ + n)) * A_ + hh * D_ + d0) = w;
}

// ---------------------------------------------------------------------------
// add+LN, wave-per-row (4 rows/block), shfl-only reduce, 4 elems/lane
// ---------------------------------------------------------------------------
__global__ __launch_bounds__(256) void add_ln_kernel(
    const ushort* __restrict__ roll, const float* __restrict__ prev,
    const float* __restrict__ g, const float* __restrict__ bta,
    float* __restrict__ out, ushort* __restrict__ outb)
{
    const int row = blockIdx.x * 4 + (threadIdx.x >> 6);
    const int lane = threadIdx.x & 63, c4 = lane * 4;
    const size_t base = (size_t)row * A_ + c4;

    uint2 rb = *(const uint2*)(roll + base);
    float4 pv = *(const float4*)(prev + base);
    float v0 = b2f((ushort)(rb.x & 0xffff)) + pv.x;
    float v1 = b2f((ushort)(rb.x >> 16))    + pv.y;
    float v2 = b2f((ushort)(rb.y & 0xffff)) + pv.z;
    float v3 = b2f((ushort)(rb.y >> 16))    + pv.w;

    float s  = v0 + v1 + v2 + v3;
    float s2 = v0 * v0 + v1 * v1 + v2 * v2 + v3 * v3;
#pragma unroll
    for (int o = 32; o > 0; o >>= 1) {
        s  += __shfl_xor(s, o, 64);
        s2 += __shfl_xor(s2, o, 64);
    }
    const float mu = s * (1.f / A_);
    const float rs = rsqrtf(s2 * (1.f / A_) - mu * mu + EPS_);

    float4 gv = *(const float4*)(g + c4);
    float4 bv = *(const float4*)(bta + c4);
    float y0 = (v0 - mu) * rs * gv.x + bv.x;
    float y1 = (v1 - mu) * rs * gv.y + bv.y;
    float y2 = (v2 - mu) * rs * gv.z + bv.z;
    float y3 = (v3 - mu) * rs * gv.w + bv.w;

    float4 yo = { y0, y1, y2, y3 };
    *(float4*)(out + base) = yo;
    uint2 yb = { f2b2(y0, y1), f2b2(y2, y3) };
    *(uint2*)(outb + base) = yb;
}

// ---------------------------------------------------------------------------
// Final: pooled = part/N -> relu(pooled @ We + be)
// ---------------------------------------------------------------------------
__global__ __launch_bounds__(256) void final_kernel(
    const float* __restrict__ part, const float* __restrict__ We,
    const float* __restrict__ be, float* __restrict__ out)
{
    __shared__ float sp[A_];
    const int b = blockIdx.x, tid = threadIdx.x;
    sp[tid] = part[(size_t)b * A_ + tid] * (1.0f / N_);
    __syncthreads();
    float acc = be[tid];
    for (int kk = 0; kk < A_; ++kk) acc += sp[kk] * We[(size_t)kk * A_ + tid];
    out[b * A_ + tid] = fmaxf(acc, 0.f);
}

// ---------------------------------------------------------------------------
extern "C" void kernel_launch(void* const* d_in, const int* in_sizes, int n_in,
                              void* d_out, int out_size, void* d_ws, size_t ws_size,
                              hipStream_t stream)
{
    const float* X    = (const float*)d_in[0];
    const float* Wq   = (const float*)d_in[1];
    const float* bq   = (const float*)d_in[2];
    const float* Wk   = (const float*)d_in[3];
    const float* bk   = (const float*)d_in[4];
    const float* Wv   = (const float*)d_in[5];
    const float* bv   = (const float*)d_in[6];
    const float* W1   = (const float*)d_in[7];
    const float* b1   = (const float*)d_in[8];
    const float* W2   = (const float*)d_in[9];
    const float* b2   = (const float*)d_in[10];
    const float* ln_g = (const float*)d_in[11];
    const float* ln_b = (const float*)d_in[12];
    const float* Wc   = (const float*)d_in[13];
    const float* bc   = (const float*)d_in[14];
    const float* We   = (const float*)d_in[15];
    const float* be   = (const float*)d_in[16];

    // ---- workspace layout ----
    char* base = (char*)d_ws;
    ushort* qb     = (ushort*)base;  base += QKV_E * 2;   // q; attnb alias
    /* kb */                         base += QKV_E * 2;
    /* vt */                         base += QKV_E * 2;
    ushort* hbuf   = (ushort*)base;  base += (size_t)M_ * FFN_ * 2;  // aliases po
    ushort* rollb  = (ushort*)base;  base += (size_t)M_ * A_ * 2;    // FFN2 out bf16
    float*  step   = (float*)base;   base += (size_t)M_ * A_ * 4;
    ushort* stepb  = (ushort*)base;  base += (size_t)M_ * A_ * 2;
    ushort* wqkv_t = (ushort*)base;  base += (size_t)3 * 3 * A_ * A_ * 2;
    ushort* w1_t   = (ushort*)base;  base += (size_t)3 * A_ * FFN_ * 2;
    ushort* w2_t   = (ushort*)base;  base += (size_t)3 * FFN_ * A_ * 2;
    ushort* wc_t   = (ushort*)base;  base += (size_t)A_ * A_ * 2;
    float*  part   = (float*)base;   base += (size_t)B_ * A_ * 4;
    float*  pm     = (float*)base;   base += (size_t)SPLIT * B_ * H_ * N_ * 4;
    float*  pl     = (float*)base;   base += (size_t)SPLIT * B_ * H_ * N_ * 4;
    ushort* kbuf   = qb + QKV_E;
    ushort* vtbuf  = qb + 2 * QKV_E;
    ushort* po     = hbuf;           // partial O: dead before FFN1 writes hbuf
    ushort* attnb  = qb;             // combine out: q dead after attn_kernel

    // ---- weight/input prep ----
    transpose_qkv_kernel<<<dim3(8, 8, 9), 256, 0, stream>>>(Wq, Wk, Wv, wqkv_t);
    transpose_bf16_kernel<<<dim3(FFN_/32, A_/32, 3), 256, 0, stream>>>(
        W1, w1_t, A_, FFN_, (size_t)A_ * FFN_, (size_t)A_ * FFN_);
    transpose_bf16_kernel<<<dim3(A_/32, FFN_/32, 3), 256, 0, stream>>>(
        W2, w2_t, FFN_, A_, (size_t)FFN_ * A_, (size_t)FFN_ * A_);
    transpose_bf16_kernel<<<dim3(A_/32, A_/32, 1), 256, 0, stream>>>(
        Wc, wc_t, A_, A_, 0, 0);
    f32_to_bf16_kernel<<<(M_ * A_) / (256 * 8), 256, 0, stream>>>(X, stepb);

    const float* cur = X;   // fp32 residual input
    for (int i = 0; i < 3; ++i) {
        gemm_mfma<2><<<dim3(M_/128, 6), 256, 0, stream>>>(
            stepb, wqkv_t + (size_t)i * 3 * A_ * A_,
            bq + i * A_, bk + i * A_, bv + i * A_, qb, A_, 0, 5);

        attn_kernel<<<16 * SPLIT * B_ * H_, 128, 0, stream>>>(
            qb, kbuf, vtbuf, po, pm, pl);
        combine_kernel<<<(B_*H_*N_*D_)/(256*8), 256, 0, stream>>>(po, pm, pl, attnb);

        gemm_mfma<2><<<dim3(M_/128, FFN_/128), 256, 0, stream>>>(
            attnb, w1_t + (size_t)i * A_ * FFN_, b1 + i * FFN_, nullptr, nullptr,
            hbuf, A_, FFN_, 2);
        // FFN2: skinny-N big-K -> BM=64 (512 blocks, 5 blocks/CU LDS)
        gemm_mfma<1><<<dim3(M_/64, A_/128), 256, 0, stream>>>(
            hbuf, w2_t + (size_t)i * FFN_ * A_, b2 + i * A_, nullptr, nullptr,
            rollb, FFN_, A_, 2);

        add_ln_kernel<<<M_/4, 256, 0, stream>>>(rollb, cur, ln_g, ln_b, step, stepb);
        cur = step;
    }

    // head: fused relu+pool via atomics into part (zeroed per call)
    hipMemsetAsync(part, 0, (size_t)B_ * A_ * 4, stream);
    gemm_mfma<1><<<dim3(M_/64, A_/128), 256, 0, stream>>>(
        stepb, wc_t, bc, nullptr, nullptr, part, A_, 0, 6);
    final_kernel<<<B_, 256, 0, stream>>>(part, We, be, (float*)d_out);
}